// Round 1
// 569.652 us; speedup vs baseline: 1.2889x; 1.2889x over previous
//
#include <hip/hip_runtime.h>
#include <math.h>

#define BN 16
#define T 12
#define CH 128
#define HW 576
#define TM1 11
#define TP 9
#define CCS 114   // channels kept after S_STA=32 cut: 96 v-channels + 18 PE

typedef __attribute__((ext_vector_type(8))) short bf16x8;   // 8 bf16 in 4 VGPRs
typedef __attribute__((ext_vector_type(4))) float floatx4;

__device__ inline float b2f(unsigned short u) {
    unsigned int v = ((unsigned int)u) << 16;
    return __builtin_bit_cast(float, v);
}
__device__ inline unsigned short f2b(float f) {
    unsigned int v = __builtin_bit_cast(unsigned int, f);
    unsigned int r = (v + 0x7FFFu + ((v >> 16) & 1u)) >> 16;   // RNE
    return (unsigned short)r;
}

__device__ __forceinline__ void async_copy16(void* lds, const void* g) {
    __builtin_amdgcn_global_load_lds(
        (const __attribute__((address_space(1))) unsigned int*)g,
        (__attribute__((address_space(3))) unsigned int*)lds,
        16, 0, 0);
}

// ---------------- K0: normalize + transpose: xT[bt][p][c] = bf16(x[bt][c][p] / ||x[bt][:,p]||)
__global__ __launch_bounds__(576) void k_norm_t(const float* __restrict__ x,
                                                unsigned short* __restrict__ xT) {
    int bt = blockIdx.x;
    int p = threadIdx.x;
    const float* xp = x + (size_t)bt * CH * HW + p;
    float s = 0.f;
#pragma unroll 8
    for (int c = 0; c < CH; c++) { float v = xp[(size_t)c * HW]; s = fmaf(v, v, s); }
    float inv = 1.0f / fmaxf(sqrtf(s), 1e-12f);
    unsigned short* dst = xT + ((size_t)bt * HW + p) * CH;
    for (int c0 = 0; c0 < CH; c0 += 8) {
        union { unsigned short u[8]; uint4 v; } pk;
#pragma unroll
        for (int j = 0; j < 8; j++) pk.u[j] = f2b(xp[(size_t)(c0 + j) * HW] * inv);
        *(uint4*)(dst + c0) = pk.v;
    }
}

// ---------------- K1: energy MFMA: E[n,m] = sc * sum_c xqT[n,c] * xkT[m,c], bf16 out
// grid (6 mtile, 6 ntile, 176), block 256 (4 waves, 2x2, each 48x48)
__global__ __launch_bounds__(256) void k_energy(const unsigned short* __restrict__ xT,
                                                unsigned short* __restrict__ attn,
                                                const int* __restrict__ temp) {
    int z = blockIdx.z; int b = z / TM1; int ti = z % TM1;
    const unsigned short* Q = xT + (size_t)(b * T + ti + 1) * HW * CH;  // rows n, k=c
    const unsigned short* K = xT + (size_t)(b * T + ti) * HW * CH;      // rows m, k=c
    unsigned short* E = attn + (size_t)z * HW * HW;
    int n0 = blockIdx.y * 96, m0 = blockIdx.x * 96;

    int lane = threadIdx.x & 63;
    int wave = threadIdx.x >> 6;
    int wy = wave >> 1, wx = wave & 1;
    int fr = lane & 15;
    int koff = (lane >> 4) * 8;

    const unsigned short* aptr[3];
    const unsigned short* bptr[3];
#pragma unroll
    for (int i = 0; i < 3; i++) {
        aptr[i] = Q + (size_t)(n0 + wy * 48 + i * 16 + fr) * CH + koff;
        bptr[i] = K + (size_t)(m0 + wx * 48 + i * 16 + fr) * CH + koff;
    }
    floatx4 acc[3][3] = {};
#pragma unroll
    for (int k0 = 0; k0 < CH; k0 += 32) {
        bf16x8 af[3], bfr[3];
#pragma unroll
        for (int i = 0; i < 3; i++) { af[i] = *(const bf16x8*)(aptr[i]); aptr[i] += 32; }
#pragma unroll
        for (int j = 0; j < 3; j++) { bfr[j] = *(const bf16x8*)(bptr[j]); bptr[j] += 32; }
#pragma unroll
        for (int i = 0; i < 3; i++)
#pragma unroll
            for (int j = 0; j < 3; j++)
                acc[i][j] = __builtin_amdgcn_mfma_f32_16x16x32_bf16(af[i], bfr[j], acc[i][j], 0, 0, 0);
    }
    float sc = 0.08838834764831845f / (float)temp[0];
    int crow = (lane >> 4) * 4, ccol = lane & 15;
#pragma unroll
    for (int i = 0; i < 3; i++) {
#pragma unroll
        for (int reg = 0; reg < 4; reg++) {
            int n = n0 + wy * 48 + i * 16 + crow + reg;
#pragma unroll
            for (int j = 0; j < 3; j++) {
                int m = m0 + wx * 48 + j * 16 + ccol;
                E[(size_t)n * HW + m] = f2b(acc[i][j][reg] * sc);
            }
        }
    }
}

// ---------------- K2: softmax in-place, one WAVE per row of 576 (9 elems/lane) ----------------
__global__ __launch_bounds__(256) void k_softmax(unsigned short* __restrict__ attn) {
    int row = blockIdx.x * 4 + (threadIdx.x >> 6);
    int lane = threadIdx.x & 63;
    unsigned short* a = attn + (size_t)row * HW + lane;

    float v[9];
#pragma unroll
    for (int j = 0; j < 9; j++) v[j] = b2f(a[64 * j]);

    float m = v[0];
#pragma unroll
    for (int j = 1; j < 9; j++) m = fmaxf(m, v[j]);
#pragma unroll
    for (int i = 1; i < 64; i <<= 1) m = fmaxf(m, __shfl_xor(m, i));

    float s = 0.f;
#pragma unroll
    for (int j = 0; j < 9; j++) { v[j] = __expf(v[j] - m); s += v[j]; }
#pragma unroll
    for (int i = 1; i < 64; i <<= 1) s += __shfl_xor(s, i);

    float inv = 1.0f / s;
#pragma unroll
    for (int j = 0; j < 9; j++) a[64 * j] = f2b(v[j] * inv);
}

// ---------------- K3: v = Wv[32:128] @ x + bv → cs16 (bf16) + direct out ch 0..95 for t>=3
// grid (9 ntile, 2 mtile, 192), block 256
__global__ __launch_bounds__(256) void k_vgemm(const float* __restrict__ x,
                                               const float* __restrict__ Wv,
                                               const float* __restrict__ bv,
                                               unsigned short* __restrict__ cs16,
                                               float* __restrict__ out) {
    int bt = blockIdx.z;
    int b = bt / T, t = bt % T;
    const float* X = x + (size_t)bt * CH * HW;
    unsigned short* C16 = cs16 + (size_t)bt * CCS * HW;
    float* O = (t >= 3) ? out + (size_t)(b * TP + t - 3) * 456 * HW : nullptr;
    int m0 = blockIdx.y * 64, n0 = blockIdx.x * 64;
    __shared__ float As[16][66];
    __shared__ float Bs[16][66];
    int tid = threadIdx.x;
    int kq = tid % 16, lr = tid / 16;
    int tx = tid % 16, ty = tid / 16;
    int lp = tid % 64, lc = tid / 64;
    float acc[4][4] = {};
    for (int c0 = 0; c0 < CH; c0 += 16) {
#pragma unroll
        for (int i = 0; i < 4; i++) {
            int r = m0 + lr + 16 * i;
            As[kq][lr + 16 * i] = (r < 96) ? Wv[(size_t)(32 + r) * CH + c0 + kq] : 0.f;
        }
#pragma unroll
        for (int i = 0; i < 4; i++) {
            int c = lc + 4 * i;
            Bs[c][lp] = X[(size_t)(c0 + c) * HW + n0 + lp];
        }
        __syncthreads();
#pragma unroll
        for (int kk = 0; kk < 16; kk++) {
            float2 a01 = *(const float2*)&As[kk][ty * 4];
            float2 a23 = *(const float2*)&As[kk][ty * 4 + 2];
            float2 b01 = *(const float2*)&Bs[kk][tx * 4];
            float2 b23 = *(const float2*)&Bs[kk][tx * 4 + 2];
            float av[4] = {a01.x, a01.y, a23.x, a23.y};
            float bw[4] = {b01.x, b01.y, b23.x, b23.y};
#pragma unroll
            for (int i = 0; i < 4; i++)
#pragma unroll
                for (int j = 0; j < 4; j++)
                    acc[i][j] = fmaf(av[i], bw[j], acc[i][j]);
        }
        __syncthreads();
    }
#pragma unroll
    for (int i = 0; i < 4; i++) {
        int r = m0 + ty * 4 + i;
        if (r < 96) {
            float bb = bv[32 + r];
            floatx4 o;
            o[0] = acc[i][0] + bb; o[1] = acc[i][1] + bb;
            o[2] = acc[i][2] + bb; o[3] = acc[i][3] + bb;
            union { unsigned short u[4]; uint2 v; } pk;
            pk.u[0] = f2b(o[0]); pk.u[1] = f2b(o[1]); pk.u[2] = f2b(o[2]); pk.u[3] = f2b(o[3]);
            *(uint2*)(C16 + (size_t)r * HW + n0 + tx * 4) = pk.v;
            if (O) __builtin_nontemporal_store(o, (floatx4*)(O + (size_t)r * HW + n0 + tx * 4));
        }
    }
}

// ---------------- K4: positional encodings → cs16 ch 96..113 + direct out for t>=3 ----------------
__global__ __launch_bounds__(576) void k_pe(unsigned short* __restrict__ cs16,
                                            float* __restrict__ out) {
    int bt = blockIdx.x;
    int b = bt / T, t = bt % T;
    int p = threadIdx.x;
    unsigned short* C16 = cs16 + ((size_t)bt * CCS + 96) * HW + p;
    float* O = (t >= 3) ? out + ((size_t)(b * TP + t - 3) * 456 + 96) * HW + p : nullptr;
    int iy = p / 24, ix = p % 24;
    float y = -1.f + 2.f * (float)iy / 23.f;
    float xx = -1.f + 2.f * (float)ix / 23.f;
    float vals[18];
    vals[0] = y; vals[1] = xx;
    const float PI = 3.14159265358979323846f;
#pragma unroll
    for (int i = 0; i < 4; i++) {
        float k = (float)(1 << i) * PI;
        float fy = k * y, fx = k * xx;
        vals[2 + 4 * i + 0] = sinf(fy);
        vals[2 + 4 * i + 1] = sinf(fx);
        vals[2 + 4 * i + 2] = cosf(fy);
        vals[2 + 4 * i + 3] = cosf(fx);
    }
#pragma unroll
    for (int c = 0; c < 18; c++) {
        C16[(size_t)c * HW] = f2b(vals[c]);
        if (O) __builtin_nontemporal_store(vals[c], O + (size_t)c * HW);
    }
}

// ---------------- K5: stage GEMM via MFMA, LDS-pipelined (2-phase, global_load_lds):
//   prop[r,n] = sum_m A[r,m] * attn[n,m]
// Tiles: BM=128 (M tiled: MT=ceil(M/128)), BN=96 (6 exact n-tiles), BK=64, 9 K-steps.
// Block 256 = 4 waves (2M x 2N), per-wave 4x3 16x16 fragments.
// LDS: double buffer of (A 128x64 + B 96x64) bf16 = 2*28672 = 57344 B.
// Swizzle: linear global_load_lds dest + inverse-XOR'd global source; ds_read applies
//   the same XOR (chunk ^= row&7) -> 2-way bank conflict (free).
// Grid: 1-D, nwg = 144*MT*6 (divisible by 8) with XCD-chunked bijective swizzle;
//   nt fastest (A-tile reuse), then mt (B/attn slice reuse in XCD L2), then z.
template<int M_, bool F32OUT>
__global__ __launch_bounds__(256) void k_stage(const unsigned short* __restrict__ cs16,
                                               const unsigned short* __restrict__ prop_in,
                                               const unsigned short* __restrict__ attn,
                                               float* __restrict__ dst_f32,
                                               unsigned short* __restrict__ dst_b16,
                                               int tshift, int prop_ch,
                                               int dst_stride_ch, int dst_ch_off) {
    constexpr int MT = (M_ + 127) / 128;
    constexpr int WPZ = MT * 6;          // workgroups per z
    constexpr int BUFSZ = 28672;         // bytes per LDS buffer (A 16384 + B 12288)

    // XCD-chunked swizzle: HW assigns xcd = launchIdx % 8; remap so each XCD gets a
    // contiguous chunk of logical wgids (nwg % 8 == 0 for all three instantiations).
    int nwg = gridDim.x;
    int wg = (blockIdx.x & 7) * (nwg >> 3) + (blockIdx.x >> 3);
    int z = wg / WPZ;
    int rem = wg % WPZ;
    int mt = rem / 6, nt = rem % 6;
    int m0 = mt * 128, n0 = nt * 96;

    int b = z / TP, tp = z % TP;
    const unsigned short* csz = cs16 + (size_t)((b * T + tp + tshift) * CCS) * HW;
    const unsigned short* prz = prop_in ? prop_in + (size_t)z * prop_ch * HW : csz;
    const unsigned short* Bm = attn + (size_t)(b * TM1 + tp + tshift) * HW * HW;

    __shared__ uint4 smq[2 * BUFSZ / 16];
    char* smc = (char*)smq;

    int tid = threadIdx.x;
    int lane = tid & 63, wave = tid >> 6;
    int wm = wave >> 1, wn = wave & 1;
    int fr = lane & 15, hi = lane >> 4;

    // ---- staging source pointers (inverse-swizzled global addresses) ----
    int cp = tid & 7;            // destination chunk (column 16B slot) this thread fills
    int rloc = tid >> 3;         // row within each 32-row issue group
    const unsigned short* srcA[4];
#pragma unroll
    for (int i = 0; i < 4; i++) {
        int r = i * 32 + rloc;                 // 0..127 tile row
        int rg = m0 + r;
        const unsigned short* p;
        if (rg < CCS) p = csz + (size_t)rg * HW;
        else if (rg < M_) p = prz + (size_t)(rg - CCS) * HW;
        else p = csz;                          // clamp: garbage row, result masked at C-write
        srcA[i] = p + ((cp ^ (r & 7)) << 3);   // source chunk = cp ^ (row&7)
    }
    const unsigned short* srcB[3];
#pragma unroll
    for (int i = 0; i < 3; i++) {
        int r = i * 32 + rloc;                 // 0..95 tile row (n), n0+r <= 575 always
        srcB[i] = Bm + (size_t)(n0 + r) * HW + ((cp ^ (r & 7)) << 3);
    }

    // ---- LDS fragment read offsets ----
    int arow[4], brow[3];
#pragma unroll
    for (int i = 0; i < 4; i++) arow[i] = (wm * 64 + i * 16 + fr) * 128;
#pragma unroll
    for (int j = 0; j < 3; j++) brow[j] = (wn * 48 + j * 16 + fr) * 128;
    int xr = fr & 7;

    floatx4 acc[4][3] = {};
    int buf = 0;

    // prologue: stage k-tile 0
    {
        char* base = smc;
        int wo = wave * 1024;
#pragma unroll
        for (int i = 0; i < 4; i++) async_copy16(base + i * 4096 + wo, srcA[i]);
#pragma unroll
        for (int i = 0; i < 3; i++) async_copy16(base + 16384 + i * 4096 + wo, srcB[i]);
    }
    __syncthreads();

    for (int t = 0; t < 9; ++t) {
        if (t < 8) {   // stage next k-tile into the other buffer (overlaps with MFMA below)
            char* nb = smc + (buf ^ 1) * BUFSZ;
            int wo = wave * 1024;
            int ko = (t + 1) * 64;
#pragma unroll
            for (int i = 0; i < 4; i++) async_copy16(nb + i * 4096 + wo, srcA[i] + ko);
#pragma unroll
            for (int i = 0; i < 3; i++) async_copy16(nb + 16384 + i * 4096 + wo, srcB[i] + ko);
        }
        char* base = smc + buf * BUFSZ;
#pragma unroll
        for (int s = 0; s < 2; ++s) {
            int coff = ((s * 4 + hi) ^ xr) << 4;
            bf16x8 af[4], bfr[3];
#pragma unroll
            for (int i = 0; i < 4; i++) af[i] = *(const bf16x8*)(base + arow[i] + coff);
#pragma unroll
            for (int j = 0; j < 3; j++) bfr[j] = *(const bf16x8*)(base + 16384 + brow[j] + coff);
#pragma unroll
            for (int i = 0; i < 4; i++)
#pragma unroll
                for (int j = 0; j < 3; j++)
                    acc[i][j] = __builtin_amdgcn_mfma_f32_16x16x32_bf16(af[i], bfr[j], acc[i][j], 0, 0, 0);
        }
        __syncthreads();   // drains vmcnt (staging done) + protects buffer reuse
        buf ^= 1;
    }

    int crow = hi * 4, ccol = fr;
#pragma unroll
    for (int i = 0; i < 4; i++) {
#pragma unroll
        for (int reg = 0; reg < 4; reg++) {
            int r = m0 + wm * 64 + i * 16 + crow + reg;
            if (r < M_) {
#pragma unroll
                for (int j = 0; j < 3; j++) {
                    int n = n0 + wn * 48 + j * 16 + ccol;
                    size_t idx = ((size_t)z * dst_stride_ch + dst_ch_off + r) * HW + n;
                    if (F32OUT) __builtin_nontemporal_store(acc[i][j][reg], dst_f32 + idx);
                    else dst_b16[idx] = f2b(acc[i][j][reg]);
                }
            }
        }
    }
}

extern "C" void kernel_launch(void* const* d_in, const int* in_sizes, int n_in,
                              void* d_out, int out_size, void* d_ws, size_t ws_size,
                              hipStream_t stream) {
    const float* x  = (const float*)d_in[0];
    const float* Wv = (const float*)d_in[1];
    const float* bv = (const float*)d_in[2];
    const int* temp = (const int*)d_in[3];
    float* out = (float*)d_out;

    // workspace layout (bytes):
    char* w = (char*)d_ws;
    unsigned short* xT     = (unsigned short*)w;                 // 192*576*128 ush = 28.3 MB
    w += (size_t)192 * HW * CH * 2;
    unsigned short* attn16 = (unsigned short*)w;                 // 176*576*576 ush = 116.8 MB
    w += (size_t)176 * HW * HW * 2;
    unsigned short* cs16   = (unsigned short*)w;                 // 25.2 MB
    w += (size_t)192 * CCS * HW * 2;
    unsigned short* p1     = (unsigned short*)w;                 // 144*114*576 ush = 18.9 MB
    w += (size_t)144 * CCS * HW * 2;
    unsigned short* p2     = (unsigned short*)w;                 // 144*228*576 ush = 37.8 MB
    // total ~227 MB

    k_norm_t<<<192, 576, 0, stream>>>(x, xT);
    k_energy<<<dim3(6, 6, 176), 256, 0, stream>>>(xT, attn16, temp);
    k_softmax<<<BN * TM1 * HW / 4, 256, 0, stream>>>(attn16);
    k_vgemm<<<dim3(9, 2, 192), 256, 0, stream>>>(x, Wv, bv, cs16, out);
    k_pe<<<192, 576, 0, stream>>>(cs16, out);
    // nwg = 144 * MT * 6: 864 / 1728 / 2592 (all divisible by 8 for the XCD swizzle)
    k_stage<114, false><<<dim3(864),  256, 0, stream>>>(cs16, nullptr, attn16, nullptr, p1, 0, 0, 114, 0);
    k_stage<228, false><<<dim3(1728), 256, 0, stream>>>(cs16, p1, attn16, nullptr, p2, 1, 114, 228, 0);
    k_stage<342, true ><<<dim3(2592), 256, 0, stream>>>(cs16, p2, attn16, out, nullptr, 2, 228, 456, 114);
}

// Round 3
// 516.227 us; speedup vs baseline: 1.4223x; 1.1035x over previous
//
#include <hip/hip_runtime.h>
#include <math.h>

#define BN 16
#define T 12
#define CH 128
#define HW 576
#define TM1 11
#define TP 9
#define CCS 114   // channels kept after S_STA=32 cut: 96 v-channels + 18 PE

typedef __attribute__((ext_vector_type(8))) short bf16x8;   // 8 bf16 in 4 VGPRs
typedef __attribute__((ext_vector_type(4))) float floatx4;

__device__ inline float b2f(unsigned short u) {
    unsigned int v = ((unsigned int)u) << 16;
    return __builtin_bit_cast(float, v);
}
__device__ inline unsigned short f2b(float f) {
    unsigned int v = __builtin_bit_cast(unsigned int, f);
    unsigned int r = (v + 0x7FFFu + ((v >> 16) & 1u)) >> 16;   // RNE
    return (unsigned short)r;
}

__device__ __forceinline__ void async_copy16(void* lds, const void* g) {
    __builtin_amdgcn_global_load_lds(
        (const __attribute__((address_space(1))) unsigned int*)g,
        (__attribute__((address_space(3))) unsigned int*)lds,
        16, 0, 0);
}

// ---------------- K0: normalize + transpose: xT[bt][p][c] = bf16(x[bt][c][p] / ||x[bt][:,p]||)
// Re-parallelized: grid 192*9 blocks (bt, 64-wide p-slice), 256 threads.
// Thread t: p-quad pq=t&15 (4 p's), c-group cg=t>>4 (8 c's). Loads its 8c x 4p
// sub-tile as 8 float4 (held in registers), accumulates 4 sq-sums in flight.
// Reduce over the 16 c-groups: shfl_xor(16,32) within wave + tiny LDS cross-wave.
// Store: each thread owns 4 output rows' 16B chunk (8 consecutive c) -> uint4.
__global__ __launch_bounds__(256) void k_norm_t(const float* __restrict__ x,
                                                unsigned short* __restrict__ xT) {
    int bt = blockIdx.x / 9;
    int p0 = (blockIdx.x % 9) * 64;
    int t = threadIdx.x;
    int lane = t & 63, wave = t >> 6;
    int pq = t & 15;          // p-quad within slice (p = p0 + pq*4 + k)
    int cg = t >> 4;          // c-group 0..15   (c = cg*8 + j)
    const float* src = x + (size_t)bt * CH * HW + (size_t)(cg * 8) * HW + p0 + pq * 4;

    floatx4 v[8];
    float s0 = 0.f, s1 = 0.f, s2 = 0.f, s3 = 0.f;
#pragma unroll
    for (int j = 0; j < 8; j++) {
        v[j] = *(const floatx4*)(src + (size_t)j * HW);
        s0 = fmaf(v[j][0], v[j][0], s0);
        s1 = fmaf(v[j][1], v[j][1], s1);
        s2 = fmaf(v[j][2], v[j][2], s2);
        s3 = fmaf(v[j][3], v[j][3], s3);
    }
    // reduce over the 4 c-groups resident in this wave (lanes l, l^16, l^32, l^48)
#pragma unroll
    for (int m = 16; m < 64; m <<= 1) {
        s0 += __shfl_xor(s0, m);
        s1 += __shfl_xor(s1, m);
        s2 += __shfl_xor(s2, m);
        s3 += __shfl_xor(s3, m);
    }
    __shared__ float smP[4][16][4];
    __shared__ float smI[64];
    if (lane < 16) {
        smP[wave][lane][0] = s0; smP[wave][lane][1] = s1;
        smP[wave][lane][2] = s2; smP[wave][lane][3] = s3;
    }
    __syncthreads();
    if (t < 64) {
        int q = t >> 2, k = t & 3;
        float tot = smP[0][q][k] + smP[1][q][k] + smP[2][q][k] + smP[3][q][k];
        smI[t] = 1.0f / fmaxf(sqrtf(tot), 1e-12f);
    }
    __syncthreads();
    unsigned short* dst = xT + ((size_t)bt * HW + p0 + pq * 4) * CH + cg * 8;
#pragma unroll
    for (int k = 0; k < 4; k++) {
        float inv = smI[pq * 4 + k];
        union { unsigned short u[8]; uint4 q4; } pk;
#pragma unroll
        for (int j = 0; j < 8; j++) pk.u[j] = f2b(v[j][k] * inv);
        *(uint4*)(dst + (size_t)k * CH) = pk.q4;
    }
}

// ---------------- K1: energy MFMA: E[n,m] = sc * sum_c xqT[n,c] * xkT[m,c], bf16 out
// grid (6 mtile, 6 ntile, 176), block 256 (4 waves, 2x2, each 48x48)
__global__ __launch_bounds__(256) void k_energy(const unsigned short* __restrict__ xT,
                                                unsigned short* __restrict__ attn,
                                                const int* __restrict__ temp) {
    int z = blockIdx.z; int b = z / TM1; int ti = z % TM1;
    const unsigned short* Q = xT + (size_t)(b * T + ti + 1) * HW * CH;  // rows n, k=c
    const unsigned short* K = xT + (size_t)(b * T + ti) * HW * CH;      // rows m, k=c
    unsigned short* E = attn + (size_t)z * HW * HW;
    int n0 = blockIdx.y * 96, m0 = blockIdx.x * 96;

    int lane = threadIdx.x & 63;
    int wave = threadIdx.x >> 6;
    int wy = wave >> 1, wx = wave & 1;
    int fr = lane & 15;
    int koff = (lane >> 4) * 8;

    const unsigned short* aptr[3];
    const unsigned short* bptr[3];
#pragma unroll
    for (int i = 0; i < 3; i++) {
        aptr[i] = Q + (size_t)(n0 + wy * 48 + i * 16 + fr) * CH + koff;
        bptr[i] = K + (size_t)(m0 + wx * 48 + i * 16 + fr) * CH + koff;
    }
    floatx4 acc[3][3] = {};
#pragma unroll
    for (int k0 = 0; k0 < CH; k0 += 32) {
        bf16x8 af[3], bfr[3];
#pragma unroll
        for (int i = 0; i < 3; i++) { af[i] = *(const bf16x8*)(aptr[i]); aptr[i] += 32; }
#pragma unroll
        for (int j = 0; j < 3; j++) { bfr[j] = *(const bf16x8*)(bptr[j]); bptr[j] += 32; }
#pragma unroll
        for (int i = 0; i < 3; i++)
#pragma unroll
            for (int j = 0; j < 3; j++)
                acc[i][j] = __builtin_amdgcn_mfma_f32_16x16x32_bf16(af[i], bfr[j], acc[i][j], 0, 0, 0);
    }
    float sc = 0.08838834764831845f / (float)temp[0];
    int crow = (lane >> 4) * 4, ccol = lane & 15;
#pragma unroll
    for (int i = 0; i < 3; i++) {
#pragma unroll
        for (int reg = 0; reg < 4; reg++) {
            int n = n0 + wy * 48 + i * 16 + crow + reg;
#pragma unroll
            for (int j = 0; j < 3; j++) {
                int m = m0 + wx * 48 + j * 16 + ccol;
                E[(size_t)n * HW + m] = f2b(acc[i][j][reg] * sc);
            }
        }
    }
}

// ---------------- K2: softmax in-place, one WAVE per row of 576 (9 elems/lane) ----------------
__global__ __launch_bounds__(256) void k_softmax(unsigned short* __restrict__ attn) {
    int row = blockIdx.x * 4 + (threadIdx.x >> 6);
    int lane = threadIdx.x & 63;
    unsigned short* a = attn + (size_t)row * HW + lane;

    float v[9];
#pragma unroll
    for (int j = 0; j < 9; j++) v[j] = b2f(a[64 * j]);

    float m = v[0];
#pragma unroll
    for (int j = 1; j < 9; j++) m = fmaxf(m, v[j]);
#pragma unroll
    for (int i = 1; i < 64; i <<= 1) m = fmaxf(m, __shfl_xor(m, i));

    float s = 0.f;
#pragma unroll
    for (int j = 0; j < 9; j++) { v[j] = __expf(v[j] - m); s += v[j]; }
#pragma unroll
    for (int i = 1; i < 64; i <<= 1) s += __shfl_xor(s, i);

    float inv = 1.0f / s;
#pragma unroll
    for (int j = 0; j < 9; j++) a[64 * j] = f2b(v[j] * inv);
}

// ---------------- K3: v = Wv[32:128] @ x + bv → cs16 (bf16) + direct out ch 0..95 for t>=3
// grid (9 ntile, 2 mtile, 192), block 256
__global__ __launch_bounds__(256) void k_vgemm(const float* __restrict__ x,
                                               const float* __restrict__ Wv,
                                               const float* __restrict__ bv,
                                               unsigned short* __restrict__ cs16,
                                               float* __restrict__ out) {
    int bt = blockIdx.z;
    int b = bt / T, t = bt % T;
    const float* X = x + (size_t)bt * CH * HW;
    unsigned short* C16 = cs16 + (size_t)bt * CCS * HW;
    float* O = (t >= 3) ? out + (size_t)(b * TP + t - 3) * 456 * HW : nullptr;
    int m0 = blockIdx.y * 64, n0 = blockIdx.x * 64;
    __shared__ float As[16][66];
    __shared__ float Bs[16][66];
    int tid = threadIdx.x;
    int kq = tid % 16, lr = tid / 16;
    int tx = tid % 16, ty = tid / 16;
    int lp = tid % 64, lc = tid / 64;
    float acc[4][4] = {};
    for (int c0 = 0; c0 < CH; c0 += 16) {
#pragma unroll
        for (int i = 0; i < 4; i++) {
            int r = m0 + lr + 16 * i;
            As[kq][lr + 16 * i] = (r < 96) ? Wv[(size_t)(32 + r) * CH + c0 + kq] : 0.f;
        }
#pragma unroll
        for (int i = 0; i < 4; i++) {
            int c = lc + 4 * i;
            Bs[c][lp] = X[(size_t)(c0 + c) * HW + n0 + lp];
        }
        __syncthreads();
#pragma unroll
        for (int kk = 0; kk < 16; kk++) {
            float2 a01 = *(const float2*)&As[kk][ty * 4];
            float2 a23 = *(const float2*)&As[kk][ty * 4 + 2];
            float2 b01 = *(const float2*)&Bs[kk][tx * 4];
            float2 b23 = *(const float2*)&Bs[kk][tx * 4 + 2];
            float av[4] = {a01.x, a01.y, a23.x, a23.y};
            float bw[4] = {b01.x, b01.y, b23.x, b23.y};
#pragma unroll
            for (int i = 0; i < 4; i++)
#pragma unroll
                for (int j = 0; j < 4; j++)
                    acc[i][j] = fmaf(av[i], bw[j], acc[i][j]);
        }
        __syncthreads();
    }
#pragma unroll
    for (int i = 0; i < 4; i++) {
        int r = m0 + ty * 4 + i;
        if (r < 96) {
            float bb = bv[32 + r];
            floatx4 o;
            o[0] = acc[i][0] + bb; o[1] = acc[i][1] + bb;
            o[2] = acc[i][2] + bb; o[3] = acc[i][3] + bb;
            union { unsigned short u[4]; uint2 v; } pk;
            pk.u[0] = f2b(o[0]); pk.u[1] = f2b(o[1]); pk.u[2] = f2b(o[2]); pk.u[3] = f2b(o[3]);
            *(uint2*)(C16 + (size_t)r * HW + n0 + tx * 4) = pk.v;
            if (O) __builtin_nontemporal_store(o, (floatx4*)(O + (size_t)r * HW + n0 + tx * 4));
        }
    }
}

// ---------------- K4: positional encodings → cs16 ch 96..113 + direct out for t>=3 ----------------
__global__ __launch_bounds__(576) void k_pe(unsigned short* __restrict__ cs16,
                                            float* __restrict__ out) {
    int bt = blockIdx.x;
    int b = bt / T, t = bt % T;
    int p = threadIdx.x;
    unsigned short* C16 = cs16 + ((size_t)bt * CCS + 96) * HW + p;
    float* O = (t >= 3) ? out + ((size_t)(b * TP + t - 3) * 456 + 96) * HW + p : nullptr;
    int iy = p / 24, ix = p % 24;
    float y = -1.f + 2.f * (float)iy / 23.f;
    float xx = -1.f + 2.f * (float)ix / 23.f;
    float vals[18];
    vals[0] = y; vals[1] = xx;
    const float PI = 3.14159265358979323846f;
#pragma unroll
    for (int i = 0; i < 4; i++) {
        float k = (float)(1 << i) * PI;
        float fy = k * y, fx = k * xx;
        vals[2 + 4 * i + 0] = sinf(fy);
        vals[2 + 4 * i + 1] = sinf(fx);
        vals[2 + 4 * i + 2] = cosf(fy);
        vals[2 + 4 * i + 3] = cosf(fx);
    }
#pragma unroll
    for (int c = 0; c < 18; c++) {
        C16[(size_t)c * HW] = f2b(vals[c]);
        if (O) __builtin_nontemporal_store(vals[c], O + (size_t)c * HW);
    }
}

// ---------------- K5: stage GEMM via MFMA, LDS-pipelined (2-phase, global_load_lds):
//   prop[r,n] = sum_m A[r,m] * attn[n,m]
// Tiles: BM=128 (M tiled: MT=ceil(M/128)), BN=96 (6 exact n-tiles), BK=64, 9 K-steps.
// Block 256 = 4 waves (2M x 2N), per-wave 4x3 16x16 fragments.
// LDS: double buffer of (A 128x64 + B 96x64) bf16 = 2*28672 = 57344 B.
// Swizzle: linear global_load_lds dest + inverse-XOR'd global source; ds_read applies
// the same XOR (chunk ^= row&7) -> 2-way bank conflict (free).
// Grid: 1-D, nwg = 144*MT*6 (divisible by 8) with XCD-chunked bijective swizzle;
//   nt fastest (A-tile reuse), then mt (B/attn slice reuse in XCD L2), then z.
template<int M_, bool F32OUT>
__global__ __launch_bounds__(256) void k_stage(const unsigned short* __restrict__ cs16,
                                               const unsigned short* __restrict__ prop_in,
                                               const unsigned short* __restrict__ attn,
                                               float* __restrict__ dst_f32,
                                               unsigned short* __restrict__ dst_b16,
                                               int tshift, int prop_ch,
                                               int dst_stride_ch, int dst_ch_off) {
    constexpr int MT = (M_ + 127) / 128;
    constexpr int WPZ = MT * 6;          // workgroups per z
    constexpr int BUFSZ = 28672;         // bytes per LDS buffer (A 16384 + B 12288)

    // XCD-chunked swizzle: HW assigns xcd = launchIdx % 8; remap so each XCD gets a
    // contiguous chunk of logical wgids (nwg % 8 == 0 for all three instantiations).
    int nwg = gridDim.x;
    int wg = (blockIdx.x & 7) * (nwg >> 3) + (blockIdx.x >> 3);
    int z = wg / WPZ;
    int rem = wg % WPZ;
    int mt = rem / 6, nt = rem % 6;
    int m0 = mt * 128, n0 = nt * 96;

    int b = z / TP, tp = z % TP;
    const unsigned short* csz = cs16 + (size_t)((b * T + tp + tshift) * CCS) * HW;
    const unsigned short* prz = prop_in ? prop_in + (size_t)z * prop_ch * HW : csz;
    const unsigned short* Bm = attn + (size_t)(b * TM1 + tp + tshift) * HW * HW;

    __shared__ uint4 smq[2 * BUFSZ / 16];
    char* smc = (char*)smq;

    int tid = threadIdx.x;
    int lane = tid & 63, wave = tid >> 6;
    int wm = wave >> 1, wn = wave & 1;
    int fr = lane & 15, hi = lane >> 4;

    // ---- staging source pointers (inverse-swizzled global addresses) ----
    int cp = tid & 7;            // destination chunk (column 16B slot) this thread fills
    int rloc = tid >> 3;         // row within each 32-row issue group
    const unsigned short* srcA[4];
#pragma unroll
    for (int i = 0; i < 4; i++) {
        int r = i * 32 + rloc;                 // 0..127 tile row
        int rg = m0 + r;
        const unsigned short* p;
        if (rg < CCS) p = csz + (size_t)rg * HW;
        else if (rg < M_) p = prz + (size_t)(rg - CCS) * HW;
        else p = csz;                          // clamp: garbage row, result masked at C-write
        srcA[i] = p + ((cp ^ (r & 7)) << 3);   // source chunk = cp ^ (row&7)
    }
    const unsigned short* srcB[3];
#pragma unroll
    for (int i = 0; i < 3; i++) {
        int r = i * 32 + rloc;                 // 0..95 tile row (n), n0+r <= 575 always
        srcB[i] = Bm + (size_t)(n0 + r) * HW + ((cp ^ (r & 7)) << 3);
    }

    // ---- LDS fragment read offsets ----
    int arow[4], brow[3];
#pragma unroll
    for (int i = 0; i < 4; i++) arow[i] = (wm * 64 + i * 16 + fr) * 128;
#pragma unroll
    for (int j = 0; j < 3; j++) brow[j] = (wn * 48 + j * 16 + fr) * 128;
    int xr = fr & 7;

    floatx4 acc[4][3] = {};
    int buf = 0;

    // prologue: stage k-tile 0
    {
        char* base = smc;
        int wo = wave * 1024;
#pragma unroll
        for (int i = 0; i < 4; i++) async_copy16(base + i * 4096 + wo, srcA[i]);
#pragma unroll
        for (int i = 0; i < 3; i++) async_copy16(base + 16384 + i * 4096 + wo, srcB[i]);
    }
    __syncthreads();

    for (int t = 0; t < 9; ++t) {
        if (t < 8) {   // stage next k-tile into the other buffer (overlaps with MFMA below)
            char* nb = smc + (buf ^ 1) * BUFSZ;
            int wo = wave * 1024;
            int ko = (t + 1) * 64;
#pragma unroll
            for (int i = 0; i < 4; i++) async_copy16(nb + i * 4096 + wo, srcA[i] + ko);
#pragma unroll
            for (int i = 0; i < 3; i++) async_copy16(nb + 16384 + i * 4096 + wo, srcB[i] + ko);
        }
        char* base = smc + buf * BUFSZ;
#pragma unroll
        for (int s = 0; s < 2; ++s) {
            int coff = ((s * 4 + hi) ^ xr) << 4;
            bf16x8 af[4], bfr[3];
#pragma unroll
            for (int i = 0; i < 4; i++) af[i] = *(const bf16x8*)(base + arow[i] + coff);
#pragma unroll
            for (int j = 0; j < 3; j++) bfr[j] = *(const bf16x8*)(base + 16384 + brow[j] + coff);
#pragma unroll
            for (int i = 0; i < 4; i++)
#pragma unroll
                for (int j = 0; j < 3; j++)
                    acc[i][j] = __builtin_amdgcn_mfma_f32_16x16x32_bf16(af[i], bfr[j], acc[i][j], 0, 0, 0);
        }
        __syncthreads();   // drains vmcnt (staging done) + protects buffer reuse
        buf ^= 1;
    }

    int crow = hi * 4, ccol = fr;
#pragma unroll
    for (int i = 0; i < 4; i++) {
#pragma unroll
        for (int reg = 0; reg < 4; reg++) {
            int r = m0 + wm * 64 + i * 16 + crow + reg;
            if (r < M_) {
#pragma unroll
                for (int j = 0; j < 3; j++) {
                    int n = n0 + wn * 48 + j * 16 + ccol;
                    size_t idx = ((size_t)z * dst_stride_ch + dst_ch_off + r) * HW + n;
                    if (F32OUT) __builtin_nontemporal_store(acc[i][j][reg], dst_f32 + idx);
                    else dst_b16[idx] = f2b(acc[i][j][reg]);
                }
            }
        }
    }
}

extern "C" void kernel_launch(void* const* d_in, const int* in_sizes, int n_in,
                              void* d_out, int out_size, void* d_ws, size_t ws_size,
                              hipStream_t stream) {
    const float* x  = (const float*)d_in[0];
    const float* Wv = (const float*)d_in[1];
    const float* bv = (const float*)d_in[2];
    const int* temp = (const int*)d_in[3];
    float* out = (float*)d_out;

    // workspace layout (bytes):
    char* w = (char*)d_ws;
    unsigned short* xT     = (unsigned short*)w;                 // 192*576*128 ush = 28.3 MB
    w += (size_t)192 * HW * CH * 2;
    unsigned short* attn16 = (unsigned short*)w;                 // 176*576*576 ush = 116.8 MB
    w += (size_t)176 * HW * HW * 2;
    unsigned short* cs16   = (unsigned short*)w;                 // 25.2 MB
    w += (size_t)192 * CCS * HW * 2;
    unsigned short* p1     = (unsigned short*)w;                 // 144*114*576 ush = 18.9 MB
    w += (size_t)144 * CCS * HW * 2;
    unsigned short* p2     = (unsigned short*)w;                 // 144*228*576 ush = 37.8 MB
    // total ~227 MB

    k_norm_t<<<192 * 9, 256, 0, stream>>>(x, xT);
    k_energy<<<dim3(6, 6, 176), 256, 0, stream>>>(xT, attn16, temp);
    k_softmax<<<BN * TM1 * HW / 4, 256, 0, stream>>>(attn16);
    k_vgemm<<<dim3(9, 2, 192), 256, 0, stream>>>(x, Wv, bv, cs16, out);
    k_pe<<<192, 576, 0, stream>>>(cs16, out);
    // nwg = 144 * MT * 6: 864 / 1728 / 2592 (all divisible by 8 for the XCD swizzle)
    k_stage<114, false><<<dim3(864),  256, 0, stream>>>(cs16, nullptr, attn16, nullptr, p1, 0, 0, 114, 0);
    k_stage<228, false><<<dim3(1728), 256, 0, stream>>>(cs16, p1, attn16, nullptr, p2, 1, 114, 228, 0);
    k_stage<342, true ><<<dim3(2592), 256, 0, stream>>>(cs16, p2, attn16, out, nullptr, 2, 228, 456, 114);
}

// Round 4
// 485.971 us; speedup vs baseline: 1.5109x; 1.0623x over previous
//
#include <hip/hip_runtime.h>
#include <math.h>

#define BN 16
#define T 12
#define CH 128
#define HW 576
#define TM1 11
#define TP 9
#define CCS 114   // channels kept after S_STA=32 cut: 96 v-channels + 18 PE

typedef __attribute__((ext_vector_type(8))) short bf16x8;   // 8 bf16 in 4 VGPRs
typedef __attribute__((ext_vector_type(4))) float floatx4;

__device__ inline float b2f(unsigned short u) {
    unsigned int v = ((unsigned int)u) << 16;
    return __builtin_bit_cast(float, v);
}
__device__ inline unsigned short f2b(float f) {
    unsigned int v = __builtin_bit_cast(unsigned int, f);
    unsigned int r = (v + 0x7FFFu + ((v >> 16) & 1u)) >> 16;   // RNE
    return (unsigned short)r;
}

__device__ __forceinline__ void async_copy16(void* lds, const void* g) {
    __builtin_amdgcn_global_load_lds(
        (const __attribute__((address_space(1))) unsigned int*)g,
        (__attribute__((address_space(3))) unsigned int*)lds,
        16, 0, 0);
}

// ---------------- K0: normalize + transpose: xT[bt][p][c] = bf16(x[bt][c][p] / ||x[bt][:,p]||)
// grid 192*9 blocks (bt, 64-wide p-slice), 256 threads. x read once, held in regs.
__global__ __launch_bounds__(256) void k_norm_t(const float* __restrict__ x,
                                                unsigned short* __restrict__ xT) {
    int bt = blockIdx.x / 9;
    int p0 = (blockIdx.x % 9) * 64;
    int t = threadIdx.x;
    int lane = t & 63, wave = t >> 6;
    int pq = t & 15;          // p-quad within slice (p = p0 + pq*4 + k)
    int cg = t >> 4;          // c-group 0..15   (c = cg*8 + j)
    const float* src = x + (size_t)bt * CH * HW + (size_t)(cg * 8) * HW + p0 + pq * 4;

    floatx4 v[8];
    float s0 = 0.f, s1 = 0.f, s2 = 0.f, s3 = 0.f;
#pragma unroll
    for (int j = 0; j < 8; j++) {
        v[j] = *(const floatx4*)(src + (size_t)j * HW);
        s0 = fmaf(v[j][0], v[j][0], s0);
        s1 = fmaf(v[j][1], v[j][1], s1);
        s2 = fmaf(v[j][2], v[j][2], s2);
        s3 = fmaf(v[j][3], v[j][3], s3);
    }
    // reduce over the 4 c-groups resident in this wave (lanes l, l^16, l^32, l^48)
#pragma unroll
    for (int m = 16; m < 64; m <<= 1) {
        s0 += __shfl_xor(s0, m);
        s1 += __shfl_xor(s1, m);
        s2 += __shfl_xor(s2, m);
        s3 += __shfl_xor(s3, m);
    }
    __shared__ float smP[4][16][4];
    __shared__ float smI[64];
    if (lane < 16) {
        smP[wave][lane][0] = s0; smP[wave][lane][1] = s1;
        smP[wave][lane][2] = s2; smP[wave][lane][3] = s3;
    }
    __syncthreads();
    if (t < 64) {
        int q = t >> 2, k = t & 3;
        float tot = smP[0][q][k] + smP[1][q][k] + smP[2][q][k] + smP[3][q][k];
        smI[t] = 1.0f / fmaxf(sqrtf(tot), 1e-12f);
    }
    __syncthreads();
    unsigned short* dst = xT + ((size_t)bt * HW + p0 + pq * 4) * CH + cg * 8;
#pragma unroll
    for (int k = 0; k < 4; k++) {
        float inv = smI[pq * 4 + k];
        union { unsigned short u[8]; uint4 q4; } pk;
#pragma unroll
        for (int j = 0; j < 8; j++) pk.u[j] = f2b(v[j][k] * inv);
        *(uint4*)(dst + (size_t)k * CH) = pk.q4;
    }
}

// ---------------- K1+K2 fused: energy + softmax -> attn (bf16), one pass.
// Each block: 32 q-rows (n) x ALL 576 k-cols (m) for one z. 4 waves, wave w owns
// m in [w*144, w*144+144): 2 n-frags x 9 m-frags x K=128. Softmax over m runs on
// the f32 accumulators: lane j-reduce -> shfl_xor{1,2,4,8} (16-col group) ->
// 1KB LDS cross-wave combine. Only normalized bf16 attn is written (saves the
// 233MB E round-trip of the split version + removes one bf16 rounding).
// Grid: 3168 = 176 z * 18 ntiles, XCD-chunked swizzle => each XCD gets exactly
// 22 whole z's, so each z's K/Q panels (294KB) are HBM-fetched once per XCD.
__global__ __launch_bounds__(256, 2) void k_energysm(const unsigned short* __restrict__ xT,
                                                     unsigned short* __restrict__ attn,
                                                     const int* __restrict__ temp) {
    int nwg = gridDim.x;  // 3168
    int wg = (blockIdx.x & 7) * (nwg >> 3) + (blockIdx.x >> 3);
    int z = wg / 18, nt = wg % 18;
    int b = z / TM1, ti = z % TM1;
    const unsigned short* Q = xT + (size_t)(b * T + ti + 1) * HW * CH;  // rows n
    const unsigned short* K = xT + (size_t)(b * T + ti) * HW * CH;      // rows m
    unsigned short* A = attn + (size_t)z * HW * HW;
    int n0 = nt * 32;

    int lane = threadIdx.x & 63, wave = threadIdx.x >> 6;
    int fr = lane & 15, hi = lane >> 4;
    int koff = hi * 8;
    int m0 = wave * 144;

    // preload A fragments for all 4 k-steps (32 VGPR, reused by all 9 m-frags)
    bf16x8 af[4][2];
#pragma unroll
    for (int k0 = 0; k0 < 4; k0++)
#pragma unroll
        for (int fi = 0; fi < 2; fi++)
            af[k0][fi] = *(const bf16x8*)(Q + (size_t)(n0 + fi * 16 + fr) * CH + k0 * 32 + koff);

    floatx4 acc[2][9] = {};
#pragma unroll
    for (int k0 = 0; k0 < 4; k0++) {
        bf16x8 bfr[9];
#pragma unroll
        for (int j = 0; j < 9; j++)
            bfr[j] = *(const bf16x8*)(K + (size_t)(m0 + j * 16 + fr) * CH + k0 * 32 + koff);
#pragma unroll
        for (int fi = 0; fi < 2; fi++)
#pragma unroll
            for (int j = 0; j < 9; j++)
                acc[fi][j] = __builtin_amdgcn_mfma_f32_16x16x32_bf16(af[k0][fi], bfr[j], acc[fi][j], 0, 0, 0);
    }

    // ---- softmax over m (rows complete within block) ----
    // C/D layout: col = fr, row-in-frag = hi*4 + reg. For fixed (fi,reg) the 16
    // lanes of a hi-group hold the same row, different cols.
    __shared__ float smMax[4][32];
    __shared__ float smSum[4][32];
    float sc = 0.08838834764831845f / (float)temp[0];

    float pm[2][4];
#pragma unroll
    for (int fi = 0; fi < 2; fi++)
#pragma unroll
        for (int reg = 0; reg < 4; reg++) {
            float m = acc[fi][0][reg];
#pragma unroll
            for (int j = 1; j < 9; j++) m = fmaxf(m, acc[fi][j][reg]);
#pragma unroll
            for (int msk = 1; msk < 16; msk <<= 1) m = fmaxf(m, __shfl_xor(m, msk));
            pm[fi][reg] = m;
        }
    if (fr == 0) {
#pragma unroll
        for (int fi = 0; fi < 2; fi++)
#pragma unroll
            for (int reg = 0; reg < 4; reg++)
                smMax[wave][fi * 16 + hi * 4 + reg] = pm[fi][reg];
    }
    __syncthreads();

    float rmax[2][4];
#pragma unroll
    for (int fi = 0; fi < 2; fi++)
#pragma unroll
        for (int reg = 0; reg < 4; reg++) {
            int row = fi * 16 + hi * 4 + reg;
            rmax[fi][reg] = fmaxf(fmaxf(smMax[0][row], smMax[1][row]),
                                  fmaxf(smMax[2][row], smMax[3][row]));
        }

    float ps[2][4];
#pragma unroll
    for (int fi = 0; fi < 2; fi++)
#pragma unroll
        for (int reg = 0; reg < 4; reg++) {
            float s = 0.f;
#pragma unroll
            for (int j = 0; j < 9; j++) {
                float e = __expf(sc * (acc[fi][j][reg] - rmax[fi][reg]));
                acc[fi][j][reg] = e;
                s += e;
            }
#pragma unroll
            for (int msk = 1; msk < 16; msk <<= 1) s += __shfl_xor(s, msk);
            ps[fi][reg] = s;
        }
    if (fr == 0) {
#pragma unroll
        for (int fi = 0; fi < 2; fi++)
#pragma unroll
            for (int reg = 0; reg < 4; reg++)
                smSum[wave][fi * 16 + hi * 4 + reg] = ps[fi][reg];
    }
    __syncthreads();

#pragma unroll
    for (int fi = 0; fi < 2; fi++)
#pragma unroll
        for (int reg = 0; reg < 4; reg++) {
            int row = fi * 16 + hi * 4 + reg;
            float inv = 1.0f / (smSum[0][row] + smSum[1][row] + smSum[2][row] + smSum[3][row]);
            int n = n0 + row;
#pragma unroll
            for (int j = 0; j < 9; j++)
                A[(size_t)n * HW + m0 + j * 16 + fr] = f2b(acc[fi][j][reg] * inv);
        }
}

// ---------------- K3: v = Wv[32:128] @ x + bv → cs16 (bf16) + direct out ch 0..95 for t>=3
// grid (9 ntile, 2 mtile, 192), block 256
__global__ __launch_bounds__(256) void k_vgemm(const float* __restrict__ x,
                                               const float* __restrict__ Wv,
                                               const float* __restrict__ bv,
                                               unsigned short* __restrict__ cs16,
                                               float* __restrict__ out) {
    int bt = blockIdx.z;
    int b = bt / T, t = bt % T;
    const float* X = x + (size_t)bt * CH * HW;
    unsigned short* C16 = cs16 + (size_t)bt * CCS * HW;
    float* O = (t >= 3) ? out + (size_t)(b * TP + t - 3) * 456 * HW : nullptr;
    int m0 = blockIdx.y * 64, n0 = blockIdx.x * 64;
    __shared__ float As[16][66];
    __shared__ float Bs[16][66];
    int tid = threadIdx.x;
    int kq = tid % 16, lr = tid / 16;
    int tx = tid % 16, ty = tid / 16;
    int lp = tid % 64, lc = tid / 64;
    float acc[4][4] = {};
    for (int c0 = 0; c0 < CH; c0 += 16) {
#pragma unroll
        for (int i = 0; i < 4; i++) {
            int r = m0 + lr + 16 * i;
            As[kq][lr + 16 * i] = (r < 96) ? Wv[(size_t)(32 + r) * CH + c0 + kq] : 0.f;
        }
#pragma unroll
        for (int i = 0; i < 4; i++) {
            int c = lc + 4 * i;
            Bs[c][lp] = X[(size_t)(c0 + c) * HW + n0 + lp];
        }
        __syncthreads();
#pragma unroll
        for (int kk = 0; kk < 16; kk++) {
            float2 a01 = *(const float2*)&As[kk][ty * 4];
            float2 a23 = *(const float2*)&As[kk][ty * 4 + 2];
            float2 b01 = *(const float2*)&Bs[kk][tx * 4];
            float2 b23 = *(const float2*)&Bs[kk][tx * 4 + 2];
            float av[4] = {a01.x, a01.y, a23.x, a23.y};
            float bw[4] = {b01.x, b01.y, b23.x, b23.y};
#pragma unroll
            for (int i = 0; i < 4; i++)
#pragma unroll
                for (int j = 0; j < 4; j++)
                    acc[i][j] = fmaf(av[i], bw[j], acc[i][j]);
        }
        __syncthreads();
    }
#pragma unroll
    for (int i = 0; i < 4; i++) {
        int r = m0 + ty * 4 + i;
        if (r < 96) {
            float bb = bv[32 + r];
            floatx4 o;
            o[0] = acc[i][0] + bb; o[1] = acc[i][1] + bb;
            o[2] = acc[i][2] + bb; o[3] = acc[i][3] + bb;
            union { unsigned short u[4]; uint2 v; } pk;
            pk.u[0] = f2b(o[0]); pk.u[1] = f2b(o[1]); pk.u[2] = f2b(o[2]); pk.u[3] = f2b(o[3]);
            *(uint2*)(C16 + (size_t)r * HW + n0 + tx * 4) = pk.v;
            if (O) __builtin_nontemporal_store(o, (floatx4*)(O + (size_t)r * HW + n0 + tx * 4));
        }
    }
}

// ---------------- K4: positional encodings → cs16 ch 96..113 + direct out for t>=3 ----------------
__global__ __launch_bounds__(576) void k_pe(unsigned short* __restrict__ cs16,
                                            float* __restrict__ out) {
    int bt = blockIdx.x;
    int b = bt / T, t = bt % T;
    int p = threadIdx.x;
    unsigned short* C16 = cs16 + ((size_t)bt * CCS + 96) * HW + p;
    float* O = (t >= 3) ? out + ((size_t)(b * TP + t - 3) * 456 + 96) * HW + p : nullptr;
    int iy = p / 24, ix = p % 24;
    float y = -1.f + 2.f * (float)iy / 23.f;
    float xx = -1.f + 2.f * (float)ix / 23.f;
    float vals[18];
    vals[0] = y; vals[1] = xx;
    const float PI = 3.14159265358979323846f;
#pragma unroll
    for (int i = 0; i < 4; i++) {
        float k = (float)(1 << i) * PI;
        float fy = k * y, fx = k * xx;
        vals[2 + 4 * i + 0] = sinf(fy);
        vals[2 + 4 * i + 1] = sinf(fx);
        vals[2 + 4 * i + 2] = cosf(fy);
        vals[2 + 4 * i + 3] = cosf(fx);
    }
#pragma unroll
    for (int c = 0; c < 18; c++) {
        C16[(size_t)c * HW] = f2b(vals[c]);
        if (O) __builtin_nontemporal_store(vals[c], O + (size_t)c * HW);
    }
}

// ---------------- K5: stage GEMM via MFMA, LDS-pipelined (2-phase, global_load_lds):
//   prop[r,n] = sum_m A[r,m] * attn[n,m]
// Tiles: BM=128 (M tiled: MT=ceil(M/128)), BN=96 (6 exact n-tiles), BK=64, 9 K-steps.
// Block 256 = 4 waves (2M x 2N), per-wave 4x3 16x16 fragments.
// LDS: double buffer of (A 128x64 + B 96x64) bf16 = 2*28672 = 57344 B.
// Swizzle: linear global_load_lds dest + inverse-XOR'd global source; ds_read applies
// the same XOR (chunk ^= row&7) -> 2-way bank conflict (free).
// Grid: 1-D, nwg = 144*MT*6 (divisible by 8) with XCD-chunked bijective swizzle;
//   nt fastest (A-tile reuse), then mt (B/attn slice reuse in XCD L2), then z.
template<int M_, bool F32OUT>
__global__ __launch_bounds__(256) void k_stage(const unsigned short* __restrict__ cs16,
                                               const unsigned short* __restrict__ prop_in,
                                               const unsigned short* __restrict__ attn,
                                               float* __restrict__ dst_f32,
                                               unsigned short* __restrict__ dst_b16,
                                               int tshift, int prop_ch,
                                               int dst_stride_ch, int dst_ch_off) {
    constexpr int MT = (M_ + 127) / 128;
    constexpr int WPZ = MT * 6;          // workgroups per z
    constexpr int BUFSZ = 28672;         // bytes per LDS buffer (A 16384 + B 12288)

    // XCD-chunked swizzle: HW assigns xcd = launchIdx % 8; remap so each XCD gets a
    // contiguous chunk of logical wgids (nwg % 8 == 0 for all three instantiations).
    int nwg = gridDim.x;
    int wg = (blockIdx.x & 7) * (nwg >> 3) + (blockIdx.x >> 3);
    int z = wg / WPZ;
    int rem = wg % WPZ;
    int mt = rem / 6, nt = rem % 6;
    int m0 = mt * 128, n0 = nt * 96;

    int b = z / TP, tp = z % TP;
    const unsigned short* csz = cs16 + (size_t)((b * T + tp + tshift) * CCS) * HW;
    const unsigned short* prz = prop_in ? prop_in + (size_t)z * prop_ch * HW : csz;
    const unsigned short* Bm = attn + (size_t)(b * TM1 + tp + tshift) * HW * HW;

    __shared__ uint4 smq[2 * BUFSZ / 16];
    char* smc = (char*)smq;

    int tid = threadIdx.x;
    int lane = tid & 63, wave = tid >> 6;
    int wm = wave >> 1, wn = wave & 1;
    int fr = lane & 15, hi = lane >> 4;

    // ---- staging source pointers (inverse-swizzled global addresses) ----
    int cp = tid & 7;            // destination chunk (column 16B slot) this thread fills
    int rloc = tid >> 3;         // row within each 32-row issue group
    const unsigned short* srcA[4];
#pragma unroll
    for (int i = 0; i < 4; i++) {
        int r = i * 32 + rloc;                 // 0..127 tile row
        int rg = m0 + r;
        const unsigned short* p;
        if (rg < CCS) p = csz + (size_t)rg * HW;
        else if (rg < M_) p = prz + (size_t)(rg - CCS) * HW;
        else p = csz;                          // clamp: garbage row, result masked at C-write
        srcA[i] = p + ((cp ^ (r & 7)) << 3);   // source chunk = cp ^ (row&7)
    }
    const unsigned short* srcB[3];
#pragma unroll
    for (int i = 0; i < 3; i++) {
        int r = i * 32 + rloc;                 // 0..95 tile row (n), n0+r <= 575 always
        srcB[i] = Bm + (size_t)(n0 + r) * HW + ((cp ^ (r & 7)) << 3);
    }

    // ---- LDS fragment read offsets ----
    int arow[4], brow[3];
#pragma unroll
    for (int i = 0; i < 4; i++) arow[i] = (wm * 64 + i * 16 + fr) * 128;
#pragma unroll
    for (int j = 0; j < 3; j++) brow[j] = (wn * 48 + j * 16 + fr) * 128;
    int xr = fr & 7;

    floatx4 acc[4][3] = {};
    int buf = 0;

    // prologue: stage k-tile 0
    {
        char* base = smc;
        int wo = wave * 1024;
#pragma unroll
        for (int i = 0; i < 4; i++) async_copy16(base + i * 4096 + wo, srcA[i]);
#pragma unroll
        for (int i = 0; i < 3; i++) async_copy16(base + 16384 + i * 4096 + wo, srcB[i]);
    }
    __syncthreads();

    for (int t = 0; t < 9; ++t) {
        if (t < 8) {   // stage next k-tile into the other buffer (overlaps with MFMA below)
            char* nb = smc + (buf ^ 1) * BUFSZ;
            int wo = wave * 1024;
            int ko = (t + 1) * 64;
#pragma unroll
            for (int i = 0; i < 4; i++) async_copy16(nb + i * 4096 + wo, srcA[i] + ko);
#pragma unroll
            for (int i = 0; i < 3; i++) async_copy16(nb + 16384 + i * 4096 + wo, srcB[i] + ko);
        }
        char* base = smc + buf * BUFSZ;
#pragma unroll
        for (int s = 0; s < 2; ++s) {
            int coff = ((s * 4 + hi) ^ xr) << 4;
            bf16x8 af[4], bfr[3];
#pragma unroll
            for (int i = 0; i < 4; i++) af[i] = *(const bf16x8*)(base + arow[i] + coff);
#pragma unroll
            for (int j = 0; j < 3; j++) bfr[j] = *(const bf16x8*)(base + 16384 + brow[j] + coff);
#pragma unroll
            for (int i = 0; i < 4; i++)
#pragma unroll
                for (int j = 0; j < 3; j++)
                    acc[i][j] = __builtin_amdgcn_mfma_f32_16x16x32_bf16(af[i], bfr[j], acc[i][j], 0, 0, 0);
        }
        __syncthreads();   // drains vmcnt (staging done) + protects buffer reuse
        buf ^= 1;
    }

    int crow = hi * 4, ccol = fr;
#pragma unroll
    for (int i = 0; i < 4; i++) {
#pragma unroll
        for (int reg = 0; reg < 4; reg++) {
            int r = m0 + wm * 64 + i * 16 + crow + reg;
            if (r < M_) {
#pragma unroll
                for (int j = 0; j < 3; j++) {
                    int n = n0 + wn * 48 + j * 16 + ccol;
                    size_t idx = ((size_t)z * dst_stride_ch + dst_ch_off + r) * HW + n;
                    if (F32OUT) __builtin_nontemporal_store(acc[i][j][reg], dst_f32 + idx);
                    else dst_b16[idx] = f2b(acc[i][j][reg]);
                }
            }
        }
    }
}

extern "C" void kernel_launch(void* const* d_in, const int* in_sizes, int n_in,
                              void* d_out, int out_size, void* d_ws, size_t ws_size,
                              hipStream_t stream) {
    const float* x  = (const float*)d_in[0];
    const float* Wv = (const float*)d_in[1];
    const float* bv = (const float*)d_in[2];
    const int* temp = (const int*)d_in[3];
    float* out = (float*)d_out;

    // workspace layout (bytes):
    char* w = (char*)d_ws;
    unsigned short* xT     = (unsigned short*)w;                 // 192*576*128 ush = 28.3 MB
    w += (size_t)192 * HW * CH * 2;
    unsigned short* attn16 = (unsigned short*)w;                 // 176*576*576 ush = 116.8 MB
    w += (size_t)176 * HW * HW * 2;
    unsigned short* cs16   = (unsigned short*)w;                 // 25.2 MB
    w += (size_t)192 * CCS * HW * 2;
    unsigned short* p1     = (unsigned short*)w;                 // 144*114*576 ush = 18.9 MB
    w += (size_t)144 * CCS * HW * 2;
    unsigned short* p2     = (unsigned short*)w;                 // 144*228*576 ush = 37.8 MB
    // total ~227 MB

    k_norm_t<<<192 * 9, 256, 0, stream>>>(x, xT);
    // fused energy+softmax: 3168 = 176 z * 18 ntiles (div by 8 for XCD swizzle)
    k_energysm<<<dim3(3168), 256, 0, stream>>>(xT, attn16, temp);
    k_vgemm<<<dim3(9, 2, 192), 256, 0, stream>>>(x, Wv, bv, cs16, out);
    k_pe<<<192, 576, 0, stream>>>(cs16, out);
    // nwg = 144 * MT * 6: 864 / 1728 / 2592 (all divisible by 8 for the XCD swizzle)
    k_stage<114, false><<<dim3(864),  256, 0, stream>>>(cs16, nullptr, attn16, nullptr, p1, 0, 0, 114, 0);
    k_stage<228, false><<<dim3(1728), 256, 0, stream>>>(cs16, p1, attn16, nullptr, p2, 1, 114, 228, 0);
    k_stage<342, true ><<<dim3(2592), 256, 0, stream>>>(cs16, p2, attn16, out, nullptr, 2, 228, 456, 114);
}

// Round 5
// 479.415 us; speedup vs baseline: 1.5315x; 1.0137x over previous
//
#include <hip/hip_runtime.h>
#include <math.h>

#define BN 16
#define T 12
#define CH 128
#define HW 576
#define TM1 11
#define TP 9
#define CCS 114   // channels kept after S_STA=32 cut: 96 v-channels + 18 PE

typedef __attribute__((ext_vector_type(8))) short bf16x8;   // 8 bf16 in 4 VGPRs
typedef __attribute__((ext_vector_type(4))) float floatx4;

__device__ inline float b2f(unsigned short u) {
    unsigned int v = ((unsigned int)u) << 16;
    return __builtin_bit_cast(float, v);
}
__device__ inline unsigned short f2b(float f) {
    unsigned int v = __builtin_bit_cast(unsigned int, f);
    unsigned int r = (v + 0x7FFFu + ((v >> 16) & 1u)) >> 16;   // RNE
    return (unsigned short)r;
}

__device__ __forceinline__ void async_copy16(void* lds, const void* g) {
    __builtin_amdgcn_global_load_lds(
        (const __attribute__((address_space(1))) unsigned int*)g,
        (__attribute__((address_space(3))) unsigned int*)lds,
        16, 0, 0);
}

// ---------------- K0: normalize + transpose: xT[bt][p][c] = bf16(x[bt][c][p] / ||x[bt][:,p]||)
// grid 192*9 blocks (bt, 64-wide p-slice), 256 threads. x read once, held in regs.
__global__ __launch_bounds__(256) void k_norm_t(const float* __restrict__ x,
                                                unsigned short* __restrict__ xT) {
    int bt = blockIdx.x / 9;
    int p0 = (blockIdx.x % 9) * 64;
    int t = threadIdx.x;
    int lane = t & 63, wave = t >> 6;
    int pq = t & 15;          // p-quad within slice (p = p0 + pq*4 + k)
    int cg = t >> 4;          // c-group 0..15   (c = cg*8 + j)
    const float* src = x + (size_t)bt * CH * HW + (size_t)(cg * 8) * HW + p0 + pq * 4;

    floatx4 v[8];
    float s0 = 0.f, s1 = 0.f, s2 = 0.f, s3 = 0.f;
#pragma unroll
    for (int j = 0; j < 8; j++) {
        v[j] = *(const floatx4*)(src + (size_t)j * HW);
        s0 = fmaf(v[j][0], v[j][0], s0);
        s1 = fmaf(v[j][1], v[j][1], s1);
        s2 = fmaf(v[j][2], v[j][2], s2);
        s3 = fmaf(v[j][3], v[j][3], s3);
    }
    // reduce over the 4 c-groups resident in this wave (lanes l, l^16, l^32, l^48)
#pragma unroll
    for (int m = 16; m < 64; m <<= 1) {
        s0 += __shfl_xor(s0, m);
        s1 += __shfl_xor(s1, m);
        s2 += __shfl_xor(s2, m);
        s3 += __shfl_xor(s3, m);
    }
    __shared__ float smP[4][16][4];
    __shared__ float smI[64];
    if (lane < 16) {
        smP[wave][lane][0] = s0; smP[wave][lane][1] = s1;
        smP[wave][lane][2] = s2; smP[wave][lane][3] = s3;
    }
    __syncthreads();
    if (t < 64) {
        int q = t >> 2, k = t & 3;
        float tot = smP[0][q][k] + smP[1][q][k] + smP[2][q][k] + smP[3][q][k];
        smI[t] = 1.0f / fmaxf(sqrtf(tot), 1e-12f);
    }
    __syncthreads();
    unsigned short* dst = xT + ((size_t)bt * HW + p0 + pq * 4) * CH + cg * 8;
#pragma unroll
    for (int k = 0; k < 4; k++) {
        float inv = smI[pq * 4 + k];
        union { unsigned short u[8]; uint4 q4; } pk;
#pragma unroll
        for (int j = 0; j < 8; j++) pk.u[j] = f2b(v[j][k] * inv);
        *(uint4*)(dst + (size_t)k * CH) = pk.q4;
    }
}

// ---------------- K1+K2 fused: energy + softmax -> attn (bf16), one pass, LDS-pipelined.
// Each block: 32 q-rows (n) x ALL 576 k-cols (m) for one z. 4 waves, wave w owns
// m in [w*144, w*144+144): 2 n-frags x 9 m-frags.
// K-panel staged in LDS: per K-step (BK=32 cols of c) B-tile = 576x32 bf16 = 36 KB,
// double-buffered (72 KB, 2 blocks/CU), stage(s+1) via global_load_lds overlaps
// compute(s). Swizzle (rule 21, both-sides): LDS dest linear; source 16B-chunk
// pre-XOR'd with (row>>1)&3; ds_read applies same XOR -> 2-way banks (free).
// Q fragments preloaded to registers (32 VGPR, reused 9x each).
// Softmax over m runs on f32 accumulators: lane j-reduce -> shfl_xor{1..8} ->
// 1KB LDS cross-wave combine. Only normalized bf16 attn is written.
// Grid: 3168 = 176 z * 18 ntiles, XCD-chunked swizzle => each XCD gets exactly
// 22 whole z's, so each z's K/Q panels (294KB) are HBM-fetched once per XCD.
__global__ __launch_bounds__(256, 2) void k_energysm(const unsigned short* __restrict__ xT,
                                                     unsigned short* __restrict__ attn,
                                                     const int* __restrict__ temp) {
    int nwg = gridDim.x;  // 3168
    int wg = (blockIdx.x & 7) * (nwg >> 3) + (blockIdx.x >> 3);
    int z = wg / 18, nt = wg % 18;
    int b = z / TM1, ti = z % TM1;
    const unsigned short* Q = xT + (size_t)(b * T + ti + 1) * HW * CH;  // rows n
    const unsigned short* K = xT + (size_t)(b * T + ti) * HW * CH;      // rows m
    unsigned short* A = attn + (size_t)z * HW * HW;
    int n0 = nt * 32;

    int lane = threadIdx.x & 63, wave = threadIdx.x >> 6;
    int fr = lane & 15, hi = lane >> 4;
    int m0 = wave * 144;

    __shared__ char smB[2 * 36864];     // double-buffered B tile [576][32] bf16
    __shared__ float smMax[4][32];
    __shared__ float smSum[4][32];

    // preload A fragments for all 4 k-steps (32 VGPR, reused by all 9 m-frags)
    bf16x8 af[4][2];
#pragma unroll
    for (int k0 = 0; k0 < 4; k0++)
#pragma unroll
        for (int fi = 0; fi < 2; fi++)
            af[k0][fi] = *(const bf16x8*)(Q + (size_t)(n0 + fi * 16 + fr) * CH + k0 * 32 + hi * 8);

    // ---- staging source pointers (inverse-swizzled global chunk) ----
    // thread t stages chunk cp=t&3 (16B) of rows rw=t>>2 (+64 per issue-group g).
    // source chunk = cp ^ ((row>>1)&3)  (row>>1 parity indep. of g since g*64).
    int tt = threadIdx.x;
    int rw = tt >> 2;
    int scp = (tt & 3) ^ ((rw >> 1) & 3);
    const unsigned short* srcB[9];
#pragma unroll
    for (int g = 0; g < 9; g++)
        srcB[g] = K + (size_t)(g * 64 + rw) * CH + scp * 8;

    // ---- LDS b-frag read offsets: row m (64B), chunk hi XOR'd with (m>>1)&3 ----
    int xc = (fr >> 1) & 3;    // (m>>1)&3 with m = m0 + j*16 + fr (m0+j*16 mult of 16)
    int boff[9];
#pragma unroll
    for (int j = 0; j < 9; j++)
        boff[j] = (m0 + j * 16 + fr) * 64 + ((hi ^ xc) << 4);

    // prologue: stage k-step 0 into buf0
#pragma unroll
    for (int g = 0; g < 9; g++)
        async_copy16(smB + g * 4096 + wave * 1024, srcB[g]);
    __syncthreads();

    floatx4 acc[2][9] = {};
#pragma unroll
    for (int s = 0; s < 4; s++) {
        if (s < 3) {   // stage next k-step into the other buffer (overlaps MFMA)
            char* nb = smB + ((s + 1) & 1) * 36864 + wave * 1024;
#pragma unroll
            for (int g = 0; g < 9; g++)
                async_copy16(nb + g * 4096, srcB[g] + (s + 1) * 32);
        }
        const char* cb = smB + (s & 1) * 36864;
        bf16x8 bfr[9];
#pragma unroll
        for (int j = 0; j < 9; j++) bfr[j] = *(const bf16x8*)(cb + boff[j]);
#pragma unroll
        for (int fi = 0; fi < 2; fi++)
#pragma unroll
            for (int j = 0; j < 9; j++)
                acc[fi][j] = __builtin_amdgcn_mfma_f32_16x16x32_bf16(af[s][fi], bfr[j], acc[fi][j], 0, 0, 0);
        __syncthreads();   // drains vmcnt (staging done) + protects buffer reuse
    }

    // ---- softmax over m (rows complete within block) ----
    // C/D layout: col = fr, row-in-frag = hi*4 + reg. For fixed (fi,reg) the 16
    // lanes of a hi-group hold the same row, different cols.
    float sc = 0.08838834764831845f / (float)temp[0];

    float pm[2][4];
#pragma unroll
    for (int fi = 0; fi < 2; fi++)
#pragma unroll
        for (int reg = 0; reg < 4; reg++) {
            float m = acc[fi][0][reg];
#pragma unroll
            for (int j = 1; j < 9; j++) m = fmaxf(m, acc[fi][j][reg]);
#pragma unroll
            for (int msk = 1; msk < 16; msk <<= 1) m = fmaxf(m, __shfl_xor(m, msk));
            pm[fi][reg] = m;
        }
    if (fr == 0) {
#pragma unroll
        for (int fi = 0; fi < 2; fi++)
#pragma unroll
            for (int reg = 0; reg < 4; reg++)
                smMax[wave][fi * 16 + hi * 4 + reg] = pm[fi][reg];
    }
    __syncthreads();

    float rmax[2][4];
#pragma unroll
    for (int fi = 0; fi < 2; fi++)
#pragma unroll
        for (int reg = 0; reg < 4; reg++) {
            int row = fi * 16 + hi * 4 + reg;
            rmax[fi][reg] = fmaxf(fmaxf(smMax[0][row], smMax[1][row]),
                                  fmaxf(smMax[2][row], smMax[3][row]));
        }

    float ps[2][4];
#pragma unroll
    for (int fi = 0; fi < 2; fi++)
#pragma unroll
        for (int reg = 0; reg < 4; reg++) {
            float s = 0.f;
#pragma unroll
            for (int j = 0; j < 9; j++) {
                float e = __expf(sc * (acc[fi][j][reg] - rmax[fi][reg]));
                acc[fi][j][reg] = e;
                s += e;
            }
#pragma unroll
            for (int msk = 1; msk < 16; msk <<= 1) s += __shfl_xor(s, msk);
            ps[fi][reg] = s;
        }
    if (fr == 0) {
#pragma unroll
        for (int fi = 0; fi < 2; fi++)
#pragma unroll
            for (int reg = 0; reg < 4; reg++)
                smSum[wave][fi * 16 + hi * 4 + reg] = ps[fi][reg];
    }
    __syncthreads();

#pragma unroll
    for (int fi = 0; fi < 2; fi++)
#pragma unroll
        for (int reg = 0; reg < 4; reg++) {
            int row = fi * 16 + hi * 4 + reg;
            float inv = 1.0f / (smSum[0][row] + smSum[1][row] + smSum[2][row] + smSum[3][row]);
            int n = n0 + row;
#pragma unroll
            for (int j = 0; j < 9; j++)
                A[(size_t)n * HW + m0 + j * 16 + fr] = f2b(acc[fi][j][reg] * inv);
        }
}

// ---------------- K3: v = Wv[32:128] @ x + bv → cs16 (bf16) + direct out ch 0..95 for t>=3
// grid (9 ntile, 2 mtile, 192), block 256
__global__ __launch_bounds__(256) void k_vgemm(const float* __restrict__ x,
                                               const float* __restrict__ Wv,
                                               const float* __restrict__ bv,
                                               unsigned short* __restrict__ cs16,
                                               float* __restrict__ out) {
    int bt = blockIdx.z;
    int b = bt / T, t = bt % T;
    const float* X = x + (size_t)bt * CH * HW;
    unsigned short* C16 = cs16 + (size_t)bt * CCS * HW;
    float* O = (t >= 3) ? out + (size_t)(b * TP + t - 3) * 456 * HW : nullptr;
    int m0 = blockIdx.y * 64, n0 = blockIdx.x * 64;
    __shared__ float As[16][66];
    __shared__ float Bs[16][66];
    int tid = threadIdx.x;
    int kq = tid % 16, lr = tid / 16;
    int tx = tid % 16, ty = tid / 16;
    int lp = tid % 64, lc = tid / 64;
    float acc[4][4] = {};
    for (int c0 = 0; c0 < CH; c0 += 16) {
#pragma unroll
        for (int i = 0; i < 4; i++) {
            int r = m0 + lr + 16 * i;
            As[kq][lr + 16 * i] = (r < 96) ? Wv[(size_t)(32 + r) * CH + c0 + kq] : 0.f;
        }
#pragma unroll
        for (int i = 0; i < 4; i++) {
            int c = lc + 4 * i;
            Bs[c][lp] = X[(size_t)(c0 + c) * HW + n0 + lp];
        }
        __syncthreads();
#pragma unroll
        for (int kk = 0; kk < 16; kk++) {
            float2 a01 = *(const float2*)&As[kk][ty * 4];
            float2 a23 = *(const float2*)&As[kk][ty * 4 + 2];
            float2 b01 = *(const float2*)&Bs[kk][tx * 4];
            float2 b23 = *(const float2*)&Bs[kk][tx * 4 + 2];
            float av[4] = {a01.x, a01.y, a23.x, a23.y};
            float bw[4] = {b01.x, b01.y, b23.x, b23.y};
#pragma unroll
            for (int i = 0; i < 4; i++)
#pragma unroll
                for (int j = 0; j < 4; j++)
                    acc[i][j] = fmaf(av[i], bw[j], acc[i][j]);
        }
        __syncthreads();
    }
#pragma unroll
    for (int i = 0; i < 4; i++) {
        int r = m0 + ty * 4 + i;
        if (r < 96) {
            float bb = bv[32 + r];
            floatx4 o;
            o[0] = acc[i][0] + bb; o[1] = acc[i][1] + bb;
            o[2] = acc[i][2] + bb; o[3] = acc[i][3] + bb;
            union { unsigned short u[4]; uint2 v; } pk;
            pk.u[0] = f2b(o[0]); pk.u[1] = f2b(o[1]); pk.u[2] = f2b(o[2]); pk.u[3] = f2b(o[3]);
            *(uint2*)(C16 + (size_t)r * HW + n0 + tx * 4) = pk.v;
            if (O) __builtin_nontemporal_store(o, (floatx4*)(O + (size_t)r * HW + n0 + tx * 4));
        }
    }
}

// ---------------- K4: positional encodings → cs16 ch 96..113 + direct out for t>=3 ----------------
__global__ __launch_bounds__(576) void k_pe(unsigned short* __restrict__ cs16,
                                            float* __restrict__ out) {
    int bt = blockIdx.x;
    int b = bt / T, t = bt % T;
    int p = threadIdx.x;
    unsigned short* C16 = cs16 + ((size_t)bt * CCS + 96) * HW + p;
    float* O = (t >= 3) ? out + ((size_t)(b * TP + t - 3) * 456 + 96) * HW + p : nullptr;
    int iy = p / 24, ix = p % 24;
    float y = -1.f + 2.f * (float)iy / 23.f;
    float xx = -1.f + 2.f * (float)ix / 23.f;
    float vals[18];
    vals[0] = y; vals[1] = xx;
    const float PI = 3.14159265358979323846f;
#pragma unroll
    for (int i = 0; i < 4; i++) {
        float k = (float)(1 << i) * PI;
        float fy = k * y, fx = k * xx;
        vals[2 + 4 * i + 0] = sinf(fy);
        vals[2 + 4 * i + 1] = sinf(fx);
        vals[2 + 4 * i + 2] = cosf(fy);
        vals[2 + 4 * i + 3] = cosf(fx);
    }
#pragma unroll
    for (int c = 0; c < 18; c++) {
        C16[(size_t)c * HW] = f2b(vals[c]);
        if (O) __builtin_nontemporal_store(vals[c], O + (size_t)c * HW);
    }
}

// ---------------- K5: stage GEMM via MFMA, LDS-pipelined (2-phase, global_load_lds):
//   prop[r,n] = sum_m A[r,m] * attn[n,m]
// Tiles: BM=128 (M tiled: MT=ceil(M/128)), BN=96 (6 exact n-tiles), BK=64, 9 K-steps.
// Block 256 = 4 waves (2M x 2N), per-wave 4x3 16x16 fragments.
// LDS: double buffer of (A 128x64 + B 96x64) bf16 = 2*28672 = 57344 B.
// Swizzle: linear global_load_lds dest + inverse-XOR'd global source; ds_read applies
// the same XOR (chunk ^= row&7) -> 2-way bank conflict (free).
// Grid: 1-D, nwg = 144*MT*6 (divisible by 8) with XCD-chunked bijective swizzle;
//   nt fastest (A-tile reuse), then mt (B/attn slice reuse in XCD L2), then z.
template<int M_, bool F32OUT>
__global__ __launch_bounds__(256) void k_stage(const unsigned short* __restrict__ cs16,
                                               const unsigned short* __restrict__ prop_in,
                                               const unsigned short* __restrict__ attn,
                                               float* __restrict__ dst_f32,
                                               unsigned short* __restrict__ dst_b16,
                                               int tshift, int prop_ch,
                                               int dst_stride_ch, int dst_ch_off) {
    constexpr int MT = (M_ + 127) / 128;
    constexpr int WPZ = MT * 6;          // workgroups per z
    constexpr int BUFSZ = 28672;         // bytes per LDS buffer (A 16384 + B 12288)

    // XCD-chunked swizzle: HW assigns xcd = launchIdx % 8; remap so each XCD gets a
    // contiguous chunk of logical wgids (nwg % 8 == 0 for all three instantiations).
    int nwg = gridDim.x;
    int wg = (blockIdx.x & 7) * (nwg >> 3) + (blockIdx.x >> 3);
    int z = wg / WPZ;
    int rem = wg % WPZ;
    int mt = rem / 6, nt = rem % 6;
    int m0 = mt * 128, n0 = nt * 96;

    int b = z / TP, tp = z % TP;
    const unsigned short* csz = cs16 + (size_t)((b * T + tp + tshift) * CCS) * HW;
    const unsigned short* prz = prop_in ? prop_in + (size_t)z * prop_ch * HW : csz;
    const unsigned short* Bm = attn + (size_t)(b * TM1 + tp + tshift) * HW * HW;

    __shared__ uint4 smq[2 * BUFSZ / 16];
    char* smc = (char*)smq;

    int tid = threadIdx.x;
    int lane = tid & 63, wave = tid >> 6;
    int wm = wave >> 1, wn = wave & 1;
    int fr = lane & 15, hi = lane >> 4;

    // ---- staging source pointers (inverse-swizzled global addresses) ----
    int cp = tid & 7;            // destination chunk (column 16B slot) this thread fills
    int rloc = tid >> 3;         // row within each 32-row issue group
    const unsigned short* srcA[4];
#pragma unroll
    for (int i = 0; i < 4; i++) {
        int r = i * 32 + rloc;                 // 0..127 tile row
        int rg = m0 + r;
        const unsigned short* p;
        if (rg < CCS) p = csz + (size_t)rg * HW;
        else if (rg < M_) p = prz + (size_t)(rg - CCS) * HW;
        else p = csz;                          // clamp: garbage row, result masked at C-write
        srcA[i] = p + ((cp ^ (r & 7)) << 3);   // source chunk = cp ^ (row&7)
    }
    const unsigned short* srcB[3];
#pragma unroll
    for (int i = 0; i < 3; i++) {
        int r = i * 32 + rloc;                 // 0..95 tile row (n), n0+r <= 575 always
        srcB[i] = Bm + (size_t)(n0 + r) * HW + ((cp ^ (r & 7)) << 3);
    }

    // ---- LDS fragment read offsets ----
    int arow[4], brow[3];
#pragma unroll
    for (int i = 0; i < 4; i++) arow[i] = (wm * 64 + i * 16 + fr) * 128;
#pragma unroll
    for (int j = 0; j < 3; j++) brow[j] = (wn * 48 + j * 16 + fr) * 128;
    int xr = fr & 7;

    floatx4 acc[4][3] = {};
    int buf = 0;

    // prologue: stage k-tile 0
    {
        char* base = smc;
        int wo = wave * 1024;
#pragma unroll
        for (int i = 0; i < 4; i++) async_copy16(base + i * 4096 + wo, srcA[i]);
#pragma unroll
        for (int i = 0; i < 3; i++) async_copy16(base + 16384 + i * 4096 + wo, srcB[i]);
    }
    __syncthreads();

    for (int t = 0; t < 9; ++t) {
        if (t < 8) {   // stage next k-tile into the other buffer (overlaps with MFMA below)
            char* nb = smc + (buf ^ 1) * BUFSZ;
            int wo = wave * 1024;
            int ko = (t + 1) * 64;
#pragma unroll
            for (int i = 0; i < 4; i++) async_copy16(nb + i * 4096 + wo, srcA[i] + ko);
#pragma unroll
            for (int i = 0; i < 3; i++) async_copy16(nb + 16384 + i * 4096 + wo, srcB[i] + ko);
        }
        char* base = smc + buf * BUFSZ;
#pragma unroll
        for (int s = 0; s < 2; ++s) {
            int coff = ((s * 4 + hi) ^ xr) << 4;
            bf16x8 af[4], bfr[3];
#pragma unroll
            for (int i = 0; i < 4; i++) af[i] = *(const bf16x8*)(base + arow[i] + coff);
#pragma unroll
            for (int j = 0; j < 3; j++) bfr[j] = *(const bf16x8*)(base + 16384 + brow[j] + coff);
#pragma unroll
            for (int i = 0; i < 4; i++)
#pragma unroll
                for (int j = 0; j < 3; j++)
                    acc[i][j] = __builtin_amdgcn_mfma_f32_16x16x32_bf16(af[i], bfr[j], acc[i][j], 0, 0, 0);
        }
        __syncthreads();   // drains vmcnt (staging done) + protects buffer reuse
        buf ^= 1;
    }

    int crow = hi * 4, ccol = fr;
#pragma unroll
    for (int i = 0; i < 4; i++) {
#pragma unroll
        for (int reg = 0; reg < 4; reg++) {
            int r = m0 + wm * 64 + i * 16 + crow + reg;
            if (r < M_) {
#pragma unroll
                for (int j = 0; j < 3; j++) {
                    int n = n0 + wn * 48 + j * 16 + ccol;
                    size_t idx = ((size_t)z * dst_stride_ch + dst_ch_off + r) * HW + n;
                    if (F32OUT) __builtin_nontemporal_store(acc[i][j][reg], dst_f32 + idx);
                    else dst_b16[idx] = f2b(acc[i][j][reg]);
                }
            }
        }
    }
}

extern "C" void kernel_launch(void* const* d_in, const int* in_sizes, int n_in,
                              void* d_out, int out_size, void* d_ws, size_t ws_size,
                              hipStream_t stream) {
    const float* x  = (const float*)d_in[0];
    const float* Wv = (const float*)d_in[1];
    const float* bv = (const float*)d_in[2];
    const int* temp = (const int*)d_in[3];
    float* out = (float*)d_out;

    // workspace layout (bytes):
    char* w = (char*)d_ws;
    unsigned short* xT     = (unsigned short*)w;                 // 192*576*128 ush = 28.3 MB
    w += (size_t)192 * HW * CH * 2;
    unsigned short* attn16 = (unsigned short*)w;                 // 176*576*576 ush = 116.8 MB
    w += (size_t)176 * HW * HW * 2;
    unsigned short* cs16   = (unsigned short*)w;                 // 25.2 MB
    w += (size_t)192 * CCS * HW * 2;
    unsigned short* p1     = (unsigned short*)w;                 // 144*114*576 ush = 18.9 MB
    w += (size_t)144 * CCS * HW * 2;
    unsigned short* p2     = (unsigned short*)w;                 // 144*228*576 ush = 37.8 MB
    // total ~227 MB

    k_norm_t<<<192 * 9, 256, 0, stream>>>(x, xT);
    // fused energy+softmax: 3168 = 176 z * 18 ntiles (div by 8 for XCD swizzle)
    k_energysm<<<dim3(3168), 256, 0, stream>>>(xT, attn16, temp);
    k_vgemm<<<dim3(9, 2, 192), 256, 0, stream>>>(x, Wv, bv, cs16, out);
    k_pe<<<192, 576, 0, stream>>>(cs16, out);
    // nwg = 144 * MT * 6: 864 / 1728 / 2592 (all divisible by 8 for the XCD swizzle)
    k_stage<114, false><<<dim3(864),  256, 0, stream>>>(cs16, nullptr, attn16, nullptr, p1, 0, 0, 114, 0);
    k_stage<228, false><<<dim3(1728), 256, 0, stream>>>(cs16, p1, attn16, nullptr, p2, 1, 114, 228, 0);
    k_stage<342, true ><<<dim3(2592), 256, 0, stream>>>(cs16, p2, attn16, out, nullptr, 2, 228, 456, 114);
}

// Round 6
// 465.067 us; speedup vs baseline: 1.5788x; 1.0309x over previous
//
#include <hip/hip_runtime.h>
#include <math.h>

#define BN 16
#define T 12
#define CH 128
#define HW 576
#define TM1 11
#define TP 9
#define CCS 114   // channels kept after S_STA=32 cut: 96 v-channels + 18 PE

typedef __attribute__((ext_vector_type(8))) short bf16x8;   // 8 bf16 in 4 VGPRs
typedef __attribute__((ext_vector_type(4))) float floatx4;

__device__ inline float b2f(unsigned short u) {
    unsigned int v = ((unsigned int)u) << 16;
    return __builtin_bit_cast(float, v);
}
__device__ inline unsigned short f2b(float f) {
    unsigned int v = __builtin_bit_cast(unsigned int, f);
    unsigned int r = (v + 0x7FFFu + ((v >> 16) & 1u)) >> 16;   // RNE
    return (unsigned short)r;
}

__device__ __forceinline__ void async_copy16(void* lds, const void* g) {
    __builtin_amdgcn_global_load_lds(
        (const __attribute__((address_space(1))) unsigned int*)g,
        (__attribute__((address_space(3))) unsigned int*)lds,
        16, 0, 0);
}

// ---------------- K0: normalize + transpose: xT[bt][p][c] = bf16(x[bt][c][p] / ||x[bt][:,p]||)
// grid 192*9 blocks (bt, 64-wide p-slice), 256 threads. x read once, held in regs.
__global__ __launch_bounds__(256) void k_norm_t(const float* __restrict__ x,
                                                unsigned short* __restrict__ xT) {
    int bt = blockIdx.x / 9;
    int p0 = (blockIdx.x % 9) * 64;
    int t = threadIdx.x;
    int lane = t & 63, wave = t >> 6;
    int pq = t & 15;          // p-quad within slice (p = p0 + pq*4 + k)
    int cg = t >> 4;          // c-group 0..15   (c = cg*8 + j)
    const float* src = x + (size_t)bt * CH * HW + (size_t)(cg * 8) * HW + p0 + pq * 4;

    floatx4 v[8];
    float s0 = 0.f, s1 = 0.f, s2 = 0.f, s3 = 0.f;
#pragma unroll
    for (int j = 0; j < 8; j++) {
        v[j] = *(const floatx4*)(src + (size_t)j * HW);
        s0 = fmaf(v[j][0], v[j][0], s0);
        s1 = fmaf(v[j][1], v[j][1], s1);
        s2 = fmaf(v[j][2], v[j][2], s2);
        s3 = fmaf(v[j][3], v[j][3], s3);
    }
    // reduce over the 4 c-groups resident in this wave (lanes l, l^16, l^32, l^48)
#pragma unroll
    for (int m = 16; m < 64; m <<= 1) {
        s0 += __shfl_xor(s0, m);
        s1 += __shfl_xor(s1, m);
        s2 += __shfl_xor(s2, m);
        s3 += __shfl_xor(s3, m);
    }
    __shared__ float smP[4][16][4];
    __shared__ float smI[64];
    if (lane < 16) {
        smP[wave][lane][0] = s0; smP[wave][lane][1] = s1;
        smP[wave][lane][2] = s2; smP[wave][lane][3] = s3;
    }
    __syncthreads();
    if (t < 64) {
        int q = t >> 2, k = t & 3;
        float tot = smP[0][q][k] + smP[1][q][k] + smP[2][q][k] + smP[3][q][k];
        smI[t] = 1.0f / fmaxf(sqrtf(tot), 1e-12f);
    }
    __syncthreads();
    unsigned short* dst = xT + ((size_t)bt * HW + p0 + pq * 4) * CH + cg * 8;
#pragma unroll
    for (int k = 0; k < 4; k++) {
        float inv = smI[pq * 4 + k];
        union { unsigned short u[8]; uint4 q4; } pk;
#pragma unroll
        for (int j = 0; j < 8; j++) pk.u[j] = f2b(v[j][k] * inv);
        *(uint4*)(dst + (size_t)k * CH) = pk.q4;
    }
}

// ---------------- K1+K2(+stage1) fused: energy + softmax -> attn (bf16) AND
//                  p1[r,n] = sum_m cs16[r,m] * P[n,m]  (the first propagation stage).
// Each block: 32 q-rows (n) x ALL 576 k-cols (m) for one z. 4 waves, wave w owns
// m in [w*144, w*144+144): 2 n-frags x 9 m-frags. K-panel staged in LDS
// (double-buffered, rule-21 swizzle). Softmax over m on f32 accumulators.
// After softmax the block's 32 complete P-rows are dumped to LDS ([32][584] bf16,
// 16B row pad -> conflict-free b128 reads) and consumed in-block by an MFMA GEMM
// against cs16 (A rows r, k=m, 18 k-steps), writing p1 directly. This removes the
// stage1 kernel and its 95.5MB attn re-read; numerically identical (same bf16 P,
// same m-order). Blocks with ti>8 skip the P-GEMM (p1 only defined for tp<=8).
// Grid: 3168 = 176 z * 18 ntiles, XCD-chunked swizzle => each XCD gets exactly
// 22 whole z's (K/Q panels + cs16 slice L2-resident per XCD).
__global__ __launch_bounds__(256, 2) void k_energysm(const unsigned short* __restrict__ xT,
                                                     unsigned short* __restrict__ attn,
                                                     const unsigned short* __restrict__ cs16,
                                                     unsigned short* __restrict__ p1,
                                                     const int* __restrict__ temp) {
    int nwg = gridDim.x;  // 3168
    int wg = (blockIdx.x & 7) * (nwg >> 3) + (blockIdx.x >> 3);
    int z = wg / 18, nt = wg % 18;
    int b = z / TM1, ti = z % TM1;
    const unsigned short* Q = xT + (size_t)(b * T + ti + 1) * HW * CH;  // rows n
    const unsigned short* K = xT + (size_t)(b * T + ti) * HW * CH;      // rows m
    unsigned short* A = attn + (size_t)z * HW * HW;
    int n0 = nt * 32;

    int lane = threadIdx.x & 63, wave = threadIdx.x >> 6;
    int fr = lane & 15, hi = lane >> 4;
    int m0 = wave * 144;

    __shared__ char smB[2 * 36864];     // QK: double-buffered B tile; later: P tile [32][584]
    __shared__ float smMax[4][32];
    __shared__ float smSum[4][32];

    // preload A fragments for all 4 k-steps (32 VGPR, reused by all 9 m-frags)
    bf16x8 af[4][2];
#pragma unroll
    for (int k0 = 0; k0 < 4; k0++)
#pragma unroll
        for (int fi = 0; fi < 2; fi++)
            af[k0][fi] = *(const bf16x8*)(Q + (size_t)(n0 + fi * 16 + fr) * CH + k0 * 32 + hi * 8);

    // ---- staging source pointers (inverse-swizzled global chunk) ----
    int tt = threadIdx.x;
    int rw = tt >> 2;
    int scp = (tt & 3) ^ ((rw >> 1) & 3);
    const unsigned short* srcB[9];
#pragma unroll
    for (int g = 0; g < 9; g++)
        srcB[g] = K + (size_t)(g * 64 + rw) * CH + scp * 8;

    // ---- LDS b-frag read offsets: row m (64B), chunk hi XOR'd with (m>>1)&3 ----
    int xc = (fr >> 1) & 3;
    int boff[9];
#pragma unroll
    for (int j = 0; j < 9; j++)
        boff[j] = (m0 + j * 16 + fr) * 64 + ((hi ^ xc) << 4);

    // prologue: stage k-step 0 into buf0
#pragma unroll
    for (int g = 0; g < 9; g++)
        async_copy16(smB + g * 4096 + wave * 1024, srcB[g]);
    __syncthreads();

    floatx4 acc[2][9] = {};
#pragma unroll
    for (int s = 0; s < 4; s++) {
        if (s < 3) {
            char* nb = smB + ((s + 1) & 1) * 36864 + wave * 1024;
#pragma unroll
            for (int g = 0; g < 9; g++)
                async_copy16(nb + g * 4096, srcB[g] + (s + 1) * 32);
        }
        const char* cb = smB + (s & 1) * 36864;
        bf16x8 bfr[9];
#pragma unroll
        for (int j = 0; j < 9; j++) bfr[j] = *(const bf16x8*)(cb + boff[j]);
#pragma unroll
        for (int fi = 0; fi < 2; fi++)
#pragma unroll
            for (int j = 0; j < 9; j++)
                acc[fi][j] = __builtin_amdgcn_mfma_f32_16x16x32_bf16(af[s][fi], bfr[j], acc[fi][j], 0, 0, 0);
        __syncthreads();
    }

    // ---- softmax over m ---- (C/D layout: col = fr, row-in-frag = hi*4 + reg)
    float sc = 0.08838834764831845f / (float)temp[0];

    float pm[2][4];
#pragma unroll
    for (int fi = 0; fi < 2; fi++)
#pragma unroll
        for (int reg = 0; reg < 4; reg++) {
            float m = acc[fi][0][reg];
#pragma unroll
            for (int j = 1; j < 9; j++) m = fmaxf(m, acc[fi][j][reg]);
#pragma unroll
            for (int msk = 1; msk < 16; msk <<= 1) m = fmaxf(m, __shfl_xor(m, msk));
            pm[fi][reg] = m;
        }
    if (fr == 0) {
#pragma unroll
        for (int fi = 0; fi < 2; fi++)
#pragma unroll
            for (int reg = 0; reg < 4; reg++)
                smMax[wave][fi * 16 + hi * 4 + reg] = pm[fi][reg];
    }
    __syncthreads();

    float rmax[2][4];
#pragma unroll
    for (int fi = 0; fi < 2; fi++)
#pragma unroll
        for (int reg = 0; reg < 4; reg++) {
            int row = fi * 16 + hi * 4 + reg;
            rmax[fi][reg] = fmaxf(fmaxf(smMax[0][row], smMax[1][row]),
                                  fmaxf(smMax[2][row], smMax[3][row]));
        }

    float ps[2][4];
#pragma unroll
    for (int fi = 0; fi < 2; fi++)
#pragma unroll
        for (int reg = 0; reg < 4; reg++) {
            float s = 0.f;
#pragma unroll
            for (int j = 0; j < 9; j++) {
                float e = __expf(sc * (acc[fi][j][reg] - rmax[fi][reg]));
                acc[fi][j][reg] = e;
                s += e;
            }
#pragma unroll
            for (int msk = 1; msk < 16; msk <<= 1) s += __shfl_xor(s, msk);
            ps[fi][reg] = s;
        }
    if (fr == 0) {
#pragma unroll
        for (int fi = 0; fi < 2; fi++)
#pragma unroll
            for (int reg = 0; reg < 4; reg++)
                smSum[wave][fi * 16 + hi * 4 + reg] = ps[fi][reg];
    }
    __syncthreads();   // also: all QK ds_reads of smB done -> safe to overwrite with P

    // ---- write normalized P: global attn (bf16) + LDS P tile [32 n][584 m-pitch] ----
    constexpr int PP = 584;  // row pitch in elements (1168 B): +16B pad -> 2-way banks
#pragma unroll
    for (int fi = 0; fi < 2; fi++)
#pragma unroll
        for (int reg = 0; reg < 4; reg++) {
            int row = fi * 16 + hi * 4 + reg;
            float inv = 1.0f / (smSum[0][row] + smSum[1][row] + smSum[2][row] + smSum[3][row]);
            int n = n0 + row;
#pragma unroll
            for (int j = 0; j < 9; j++) {
                int m = m0 + j * 16 + fr;
                unsigned short pv = f2b(acc[fi][j][reg] * inv);
                A[(size_t)n * HW + m] = pv;
                *(unsigned short*)(smB + (size_t)row * (PP * 2) + m * 2) = pv;
            }
        }

    if (ti > 8) return;      // p1 only defined for tp 0..8
    __syncthreads();         // P tile complete

    // ---- fused stage1 GEMM: p1[r, n0+nn] = sum_m cs[r,m] * P[nn,m] ----
    const unsigned short* csz = cs16 + (size_t)((b * T + ti) * CCS) * HW;
    unsigned short* p1z = p1 + (size_t)(b * TP + ti) * CCS * HW;
    int rbase = wave * 32;   // wave owns r in [wave*32, wave*32+32)

    floatx4 acc2[2][2] = {};
#pragma unroll
    for (int ks = 0; ks < 18; ks++) {
        bf16x8 afr[2], pfr[2];
#pragma unroll
        for (int rf = 0; rf < 2; rf++) {
            int r = rbase + rf * 16 + fr;
            int rr = (r < CCS) ? r : 0;          // clamp; masked at store
            afr[rf] = *(const bf16x8*)(csz + (size_t)rr * HW + ks * 32 + hi * 8);
        }
#pragma unroll
        for (int nf = 0; nf < 2; nf++)
            pfr[nf] = *(const bf16x8*)(smB + (size_t)(nf * 16 + fr) * (PP * 2) + ks * 64 + hi * 16);
#pragma unroll
        for (int rf = 0; rf < 2; rf++)
#pragma unroll
            for (int nf = 0; nf < 2; nf++)
                acc2[rf][nf] = __builtin_amdgcn_mfma_f32_16x16x32_bf16(afr[rf], pfr[nf], acc2[rf][nf], 0, 0, 0);
    }
#pragma unroll
    for (int rf = 0; rf < 2; rf++)
#pragma unroll
        for (int reg = 0; reg < 4; reg++) {
            int r = rbase + rf * 16 + hi * 4 + reg;
            if (r < CCS) {
#pragma unroll
                for (int nf = 0; nf < 2; nf++) {
                    int n = n0 + nf * 16 + fr;
                    p1z[(size_t)r * HW + n] = f2b(acc2[rf][nf][reg]);
                }
            }
        }
}

// ---------------- K3: v = Wv[32:128] @ x + bv → cs16 (bf16) + direct out ch 0..95 for t>=3
// grid (9 ntile, 2 mtile, 192), block 256
__global__ __launch_bounds__(256) void k_vgemm(const float* __restrict__ x,
                                               const float* __restrict__ Wv,
                                               const float* __restrict__ bv,
                                               unsigned short* __restrict__ cs16,
                                               float* __restrict__ out) {
    int bt = blockIdx.z;
    int b = bt / T, t = bt % T;
    const float* X = x + (size_t)bt * CH * HW;
    unsigned short* C16 = cs16 + (size_t)bt * CCS * HW;
    float* O = (t >= 3) ? out + (size_t)(b * TP + t - 3) * 456 * HW : nullptr;
    int m0 = blockIdx.y * 64, n0 = blockIdx.x * 64;
    __shared__ float As[16][66];
    __shared__ float Bs[16][66];
    int tid = threadIdx.x;
    int kq = tid % 16, lr = tid / 16;
    int tx = tid % 16, ty = tid / 16;
    int lp = tid % 64, lc = tid / 64;
    float acc[4][4] = {};
    for (int c0 = 0; c0 < CH; c0 += 16) {
#pragma unroll
        for (int i = 0; i < 4; i++) {
            int r = m0 + lr + 16 * i;
            As[kq][lr + 16 * i] = (r < 96) ? Wv[(size_t)(32 + r) * CH + c0 + kq] : 0.f;
        }
#pragma unroll
        for (int i = 0; i < 4; i++) {
            int c = lc + 4 * i;
            Bs[c][lp] = X[(size_t)(c0 + c) * HW + n0 + lp];
        }
        __syncthreads();
#pragma unroll
        for (int kk = 0; kk < 16; kk++) {
            float2 a01 = *(const float2*)&As[kk][ty * 4];
            float2 a23 = *(const float2*)&As[kk][ty * 4 + 2];
            float2 b01 = *(const float2*)&Bs[kk][tx * 4];
            float2 b23 = *(const float2*)&Bs[kk][tx * 4 + 2];
            float av[4] = {a01.x, a01.y, a23.x, a23.y};
            float bw[4] = {b01.x, b01.y, b23.x, b23.y};
#pragma unroll
            for (int i = 0; i < 4; i++)
#pragma unroll
                for (int j = 0; j < 4; j++)
                    acc[i][j] = fmaf(av[i], bw[j], acc[i][j]);
        }
        __syncthreads();
    }
#pragma unroll
    for (int i = 0; i < 4; i++) {
        int r = m0 + ty * 4 + i;
        if (r < 96) {
            float bb = bv[32 + r];
            floatx4 o;
            o[0] = acc[i][0] + bb; o[1] = acc[i][1] + bb;
            o[2] = acc[i][2] + bb; o[3] = acc[i][3] + bb;
            union { unsigned short u[4]; uint2 v; } pk;
            pk.u[0] = f2b(o[0]); pk.u[1] = f2b(o[1]); pk.u[2] = f2b(o[2]); pk.u[3] = f2b(o[3]);
            *(uint2*)(C16 + (size_t)r * HW + n0 + tx * 4) = pk.v;
            if (O) __builtin_nontemporal_store(o, (floatx4*)(O + (size_t)r * HW + n0 + tx * 4));
        }
    }
}

// ---------------- K4: positional encodings → cs16 ch 96..113 + direct out for t>=3 ----------------
__global__ __launch_bounds__(576) void k_pe(unsigned short* __restrict__ cs16,
                                            float* __restrict__ out) {
    int bt = blockIdx.x;
    int b = bt / T, t = bt % T;
    int p = threadIdx.x;
    unsigned short* C16 = cs16 + ((size_t)bt * CCS + 96) * HW + p;
    float* O = (t >= 3) ? out + ((size_t)(b * TP + t - 3) * 456 + 96) * HW + p : nullptr;
    int iy = p / 24, ix = p % 24;
    float y = -1.f + 2.f * (float)iy / 23.f;
    float xx = -1.f + 2.f * (float)ix / 23.f;
    float vals[18];
    vals[0] = y; vals[1] = xx;
    const float PI = 3.14159265358979323846f;
#pragma unroll
    for (int i = 0; i < 4; i++) {
        float k = (float)(1 << i) * PI;
        float fy = k * y, fx = k * xx;
        vals[2 + 4 * i + 0] = sinf(fy);
        vals[2 + 4 * i + 1] = sinf(fx);
        vals[2 + 4 * i + 2] = cosf(fy);
        vals[2 + 4 * i + 3] = cosf(fx);
    }
#pragma unroll
    for (int c = 0; c < 18; c++) {
        C16[(size_t)c * HW] = f2b(vals[c]);
        if (O) __builtin_nontemporal_store(vals[c], O + (size_t)c * HW);
    }
}

// ---------------- K5: stage GEMM via MFMA, LDS-pipelined (2-phase, global_load_lds):
//   prop[r,n] = sum_m A[r,m] * attn[n,m]
// Tiles: BM=128 (M tiled), BN=96, BK=64, 9 K-steps. Block 256 = 4 waves (2M x 2N).
// LDS: double buffer of (A 128x64 + B 96x64) bf16 = 57344 B. Rule-21 swizzle.
// Grid: 1-D, nwg = 144*MT*6 with XCD-chunked bijective swizzle.
template<int M_, bool F32OUT>
__global__ __launch_bounds__(256) void k_stage(const unsigned short* __restrict__ cs16,
                                               const unsigned short* __restrict__ prop_in,
                                               const unsigned short* __restrict__ attn,
                                               float* __restrict__ dst_f32,
                                               unsigned short* __restrict__ dst_b16,
                                               int tshift, int prop_ch,
                                               int dst_stride_ch, int dst_ch_off) {
    constexpr int MT = (M_ + 127) / 128;
    constexpr int WPZ = MT * 6;          // workgroups per z
    constexpr int BUFSZ = 28672;         // bytes per LDS buffer (A 16384 + B 12288)

    int nwg = gridDim.x;
    int wg = (blockIdx.x & 7) * (nwg >> 3) + (blockIdx.x >> 3);
    int z = wg / WPZ;
    int rem = wg % WPZ;
    int mt = rem / 6, nt = rem % 6;
    int m0 = mt * 128, n0 = nt * 96;

    int b = z / TP, tp = z % TP;
    const unsigned short* csz = cs16 + (size_t)((b * T + tp + tshift) * CCS) * HW;
    const unsigned short* prz = prop_in ? prop_in + (size_t)z * prop_ch * HW : csz;
    const unsigned short* Bm = attn + (size_t)(b * TM1 + tp + tshift) * HW * HW;

    __shared__ uint4 smq[2 * BUFSZ / 16];
    char* smc = (char*)smq;

    int tid = threadIdx.x;
    int lane = tid & 63, wave = tid >> 6;
    int wm = wave >> 1, wn = wave & 1;
    int fr = lane & 15, hi = lane >> 4;

    int cp = tid & 7;
    int rloc = tid >> 3;
    const unsigned short* srcA[4];
#pragma unroll
    for (int i = 0; i < 4; i++) {
        int r = i * 32 + rloc;
        int rg = m0 + r;
        const unsigned short* p;
        if (rg < CCS) p = csz + (size_t)rg * HW;
        else if (rg < M_) p = prz + (size_t)(rg - CCS) * HW;
        else p = csz;
        srcA[i] = p + ((cp ^ (r & 7)) << 3);
    }
    const unsigned short* srcB[3];
#pragma unroll
    for (int i = 0; i < 3; i++) {
        int r = i * 32 + rloc;
        srcB[i] = Bm + (size_t)(n0 + r) * HW + ((cp ^ (r & 7)) << 3);
    }

    int arow[4], brow[3];
#pragma unroll
    for (int i = 0; i < 4; i++) arow[i] = (wm * 64 + i * 16 + fr) * 128;
#pragma unroll
    for (int j = 0; j < 3; j++) brow[j] = (wn * 48 + j * 16 + fr) * 128;
    int xr = fr & 7;

    floatx4 acc[4][3] = {};
    int buf = 0;

    {
        char* base = smc;
        int wo = wave * 1024;
#pragma unroll
        for (int i = 0; i < 4; i++) async_copy16(base + i * 4096 + wo, srcA[i]);
#pragma unroll
        for (int i = 0; i < 3; i++) async_copy16(base + 16384 + i * 4096 + wo, srcB[i]);
    }
    __syncthreads();

    for (int t = 0; t < 9; ++t) {
        if (t < 8) {
            char* nb = smc + (buf ^ 1) * BUFSZ;
            int wo = wave * 1024;
            int ko = (t + 1) * 64;
#pragma unroll
            for (int i = 0; i < 4; i++) async_copy16(nb + i * 4096 + wo, srcA[i] + ko);
#pragma unroll
            for (int i = 0; i < 3; i++) async_copy16(nb + 16384 + i * 4096 + wo, srcB[i] + ko);
        }
        char* base = smc + buf * BUFSZ;
#pragma unroll
        for (int s = 0; s < 2; ++s) {
            int coff = ((s * 4 + hi) ^ xr) << 4;
            bf16x8 af[4], bfr[3];
#pragma unroll
            for (int i = 0; i < 4; i++) af[i] = *(const bf16x8*)(base + arow[i] + coff);
#pragma unroll
            for (int j = 0; j < 3; j++) bfr[j] = *(const bf16x8*)(base + 16384 + brow[j] + coff);
#pragma unroll
            for (int i = 0; i < 4; i++)
#pragma unroll
                for (int j = 0; j < 3; j++)
                    acc[i][j] = __builtin_amdgcn_mfma_f32_16x16x32_bf16(af[i], bfr[j], acc[i][j], 0, 0, 0);
        }
        __syncthreads();
        buf ^= 1;
    }

    int crow = hi * 4, ccol = fr;
#pragma unroll
    for (int i = 0; i < 4; i++) {
#pragma unroll
        for (int reg = 0; reg < 4; reg++) {
            int r = m0 + wm * 64 + i * 16 + crow + reg;
            if (r < M_) {
#pragma unroll
                for (int j = 0; j < 3; j++) {
                    int n = n0 + wn * 48 + j * 16 + ccol;
                    size_t idx = ((size_t)z * dst_stride_ch + dst_ch_off + r) * HW + n;
                    if (F32OUT) __builtin_nontemporal_store(acc[i][j][reg], dst_f32 + idx);
                    else dst_b16[idx] = f2b(acc[i][j][reg]);
                }
            }
        }
    }
}

extern "C" void kernel_launch(void* const* d_in, const int* in_sizes, int n_in,
                              void* d_out, int out_size, void* d_ws, size_t ws_size,
                              hipStream_t stream) {
    const float* x  = (const float*)d_in[0];
    const float* Wv = (const float*)d_in[1];
    const float* bv = (const float*)d_in[2];
    const int* temp = (const int*)d_in[3];
    float* out = (float*)d_out;

    // workspace layout (bytes):
    char* w = (char*)d_ws;
    unsigned short* xT     = (unsigned short*)w;                 // 192*576*128 ush = 28.3 MB
    w += (size_t)192 * HW * CH * 2;
    unsigned short* attn16 = (unsigned short*)w;                 // 176*576*576 ush = 116.8 MB
    w += (size_t)176 * HW * HW * 2;
    unsigned short* cs16   = (unsigned short*)w;                 // 25.2 MB
    w += (size_t)192 * CCS * HW * 2;
    unsigned short* p1     = (unsigned short*)w;                 // 144*114*576 ush = 18.9 MB
    w += (size_t)144 * CCS * HW * 2;
    unsigned short* p2     = (unsigned short*)w;                 // 144*228*576 ush = 37.8 MB
    // total ~227 MB

    k_norm_t<<<192 * 9, 256, 0, stream>>>(x, xT);
    k_vgemm<<<dim3(9, 2, 192), 256, 0, stream>>>(x, Wv, bv, cs16, out);
    k_pe<<<192, 576, 0, stream>>>(cs16, out);
    // fused energy+softmax+stage1: needs cs16 (vgemm+pe) ready
    k_energysm<<<dim3(3168), 256, 0, stream>>>(xT, attn16, cs16, p1, temp);
    k_stage<228, false><<<dim3(1728), 256, 0, stream>>>(cs16, p1, attn16, nullptr, p2, 1, 114, 228, 0);
    k_stage<342, true ><<<dim3(2592), 256, 0, stream>>>(cs16, p2, attn16, out, nullptr, 2, 228, 456, 114);
}